// Round 4
// baseline (444.188 us; speedup 1.0000x reference)
//
#include <hip/hip_runtime.h>
#include <cstdint>
#include <cstddef>

typedef unsigned short ushort_t;
typedef unsigned int   uint_t;

#define B_   8
#define T_   16
#define N_   196
#define C_   768
#define H_   12
#define C3_  2304
#define M_   25088   // B_*T_*N_

// spatial-attention tiling
#define VS_  232     // V^T LDS row stride: 464 B = 116 dwords == 20 mod 32 ->
                     // consecutive rows spread banks; 2-way residual = free
#define PS_  232     // P LDS row stride (same property)

// temporal-attention tiling
#define TS_  40      // LDS row stride (elems): 80 B, 16B-aligned, 2-way alias

typedef __attribute__((ext_vector_type(8))) short short8;
typedef __attribute__((ext_vector_type(4))) float floatx4;

__device__ __forceinline__ float bf2f(ushort_t u) {
  return __uint_as_float(((uint_t)u) << 16);
}
__device__ __forceinline__ ushort_t f2bf(float f) {
  uint_t u = __float_as_uint(f);
  u += 0x7FFFu + ((u >> 16) & 1u);   // round-to-nearest-even
  return (ushort_t)(u >> 16);
}
__device__ __forceinline__ uint_t pack2(float a, float b) {
  return (uint_t)f2bf(a) | ((uint_t)f2bf(b) << 16);
}

// async global->LDS, 16 B per lane. LDS dest = wave-uniform base + lane*16.
__device__ __forceinline__ void gload_lds16(const ushort_t* g, ushort_t* l) {
  __builtin_amdgcn_global_load_lds(
      (const __attribute__((address_space(1))) uint_t*)g,
      (__attribute__((address_space(3))) uint_t*)l, 16, 0, 0);
}

// raw barrier: compiler memory fence + s_barrier + scheduler pin.
// (NOT __syncthreads(): that drains vmcnt(0) and would kill the counted
// prefetch pipeline.)
__device__ __forceinline__ void bar() {
  asm volatile("" ::: "memory");
  __builtin_amdgcn_s_barrier();
  __builtin_amdgcn_sched_barrier(0);
}

// ---------------------------------------------------------------------------
// Fused prep (one dispatch):
//   blocks [0, 9408)        : x fp32 -> bf16, 8 elems/thread (19,267,584)
//   blocks [9408, 16320)    : W_qkv [768][2304] -> transposed bf16 [2304][768]
//   blocks [16320, 18624)   : W_proj [768][768] -> transposed bf16 [768][768]
// ---------------------------------------------------------------------------
__global__ void fsta_prep(const float* __restrict__ x,
                          ushort_t* __restrict__ xbf,
                          const float* __restrict__ Wqkv,
                          ushort_t* __restrict__ WtQkv,
                          const float* __restrict__ Wproj,
                          ushort_t* __restrict__ WtProj)
{
  const int bid = blockIdx.x;
  const int tid = threadIdx.x;
  if (bid < 9408) {
    int i = (bid * 256 + tid) * 8;
    const float* f = x + i;
    uint4 u;
    u.x = pack2(f[0], f[1]); u.y = pack2(f[2], f[3]);
    u.z = pack2(f[4], f[5]); u.w = pack2(f[6], f[7]);
    *(uint4*)(xbf + i) = u;
  } else if (bid < 16320) {
    int o = (bid - 9408) * 256 + tid;           // < 1,769,472
    int c = o / 768;
    int r = o - c * 768;
    WtQkv[o] = f2bf(Wqkv[(size_t)r * 2304 + c]);
  } else {
    int o = (bid - 16320) * 256 + tid;          // < 589,824
    int c = o / 768;
    int r = o - c * 768;
    WtProj[o] = f2bf(Wproj[(size_t)r * 768 + c]);
  }
}

// ---------------------------------------------------------------------------
// 256x256 8-phase bf16 MFMA GEMM (T1+T2+T3+T4+T5 port):
//   C[M,N] = A[M,K] @ Bt[N,K]^T (+ fp32 bias)
// 8 waves (2Mx4N), BK=64, per-wave output 128x64, acc[8][4] of 16x16x32.
// LDS 128 KiB = 2 buffers x {A[2 ks-halves][256][32], B[...]}.
// Phase: {ds_read subtile | stage prefetch | (vmcnt guard p4/p8) | barrier |
// 16 MFMA in setprio(1) | barrier}. Counted vmcnt(4): never 0 mid-loop.
//
// T2 swizzle (round-4 fix): 16B-chunk c of row r stored at slot
// c ^ ((r>>1)&3)  [was c^(r&3)]. With 64-B rows the HW's 16-lane groups
// (rows 0..15, fixed quad) then cover all 8 bank-slots exactly 2x (2-way =
// free, m136) instead of 4 lanes on one slot (4-way). Staging side inverse:
// global source chunk = (lane&3) ^ ((srow>>1)&3); read slot = quad ^
// ((lrow>>1)&3). Predicted SQ_LDS_BANK_CONFLICT 8.1M -> <2M.
// ---------------------------------------------------------------------------
#define STG(X, rb, bu, xo, kss, t)                                            \
  { _Pragma("unroll") for (int c_ = 0; c_ < 2; ++c_) {                        \
      const ushort_t* g_ = (X) +                                              \
          (size_t)((rb) + c_ * 128 + wv * 16 + srow) * K +                    \
          (t) * 64 + (kss) * 32 + chnk * 8;                                   \
      gload_lds16(g_, &lds[(bu) * 32768 + (xo) + (kss) * 8192 +               \
                           c_ * 4096 + wv * 512]); } }

#define PH(bu, mh, kss, DOB, GUARD, ...)                                      \
  { short8 af[4];                                                             \
    _Pragma("unroll") for (int m2 = 0; m2 < 4; ++m2) {                        \
      int rr = wm * 128 + ((mh) * 4 + m2) * 16 + lrow;                        \
      af[m2] = *(const short8*)&lds[(bu) * 32768 + (kss) * 8192 +             \
                                    rr * 32 + rch8]; }                        \
    if (DOB) {                                                                \
      _Pragma("unroll") for (int n2 = 0; n2 < 4; ++n2) {                      \
        int rr = wn * 64 + n2 * 16 + lrow;                                    \
        bf[n2] = *(const short8*)&lds[(bu) * 32768 + 16384 + (kss) * 8192 +   \
                                      rr * 32 + rch8]; } }                    \
    __VA_ARGS__                                                               \
    GUARD                                                                     \
    bar();                                                                    \
    __builtin_amdgcn_s_setprio(1);                                            \
    _Pragma("unroll") for (int m2 = 0; m2 < 4; ++m2)                          \
      _Pragma("unroll") for (int n2 = 0; n2 < 4; ++n2)                        \
        acc[(mh) * 4 + m2][n2] = __builtin_amdgcn_mfma_f32_16x16x32_bf16(     \
            af[m2], bf[n2], acc[(mh) * 4 + m2][n2], 0, 0, 0);                 \
    __builtin_amdgcn_s_setprio(0);                                            \
    bar(); }

#define GUARD_NONE
#define GUARD4 asm volatile("s_waitcnt vmcnt(4)" ::: "memory");
#define GUARD0 asm volatile("s_waitcnt vmcnt(0)" ::: "memory");

template <typename OutT>
__global__ __launch_bounds__(512) void fsta_gemm256(
    const ushort_t* __restrict__ A1,
    const ushort_t* __restrict__ Bt,
    const float* __restrict__ bias,
    OutT* __restrict__ Cout,
    int Ncols, int K)
{
  __shared__ ushort_t lds[65536];          // 128 KiB
  const int tid  = threadIdx.x;
  const int lane = tid & 63;
  const int wv   = tid >> 6;
  const int wm   = wv >> 2;                // 0..1 (M half)
  const int wn   = wv & 3;                 // 0..3 (N quarter)
  const int lrow = lane & 15;
  const int quad = lane >> 4;
  const int rch8 = (quad ^ ((lrow >> 1) & 3)) * 8;  // swizzled read chunk
  const int srow = lane >> 2;                       // staging row-in-16
  const int chnk = (lane & 3) ^ ((srow >> 1) & 3);  // inverse-swizzled src

  // bijective XCD-chunk swizzle (m204 formula)
  const int ntx = gridDim.x;
  const int nwg = ntx * gridDim.y;
  int lin = blockIdx.y * ntx + blockIdx.x;
  {
    int q = nwg >> 3, r = nwg & 7;
    int xcd = lin & 7, off = lin >> 3;
    lin = (xcd < r ? xcd * (q + 1) : r * (q + 1) + (xcd - r) * q) + off;
  }
  const int m0 = (lin % ntx) * 256;
  const int n0 = (lin / ntx) * 256;

  const int NT = K >> 6;                   // 64-wide K-tiles (12)
  const int NI = NT >> 1;                  // iterations (6)

  floatx4 acc[8][4];
#pragma unroll
  for (int i = 0; i < 8; ++i)
#pragma unroll
    for (int j = 0; j < 4; ++j)
      acc[i][j] = (floatx4){0.f, 0.f, 0.f, 0.f};

  // prologue: tile0 (both ks halves) + tile1 ks0; leave tile1-ks0 in flight
  STG(A1, m0, 0, 0,     0, 0)
  STG(Bt, n0, 0, 16384, 0, 0)
  STG(A1, m0, 0, 0,     1, 0)
  STG(Bt, n0, 0, 16384, 1, 0)
  STG(A1, m0, 1, 0,     0, 1)
  STG(Bt, n0, 1, 16384, 0, 1)
  GUARD4                                   // tile0 fully landed
  bar();

  short8 bf[4];                            // B-frags persist across mh phases
  for (int i = 0; i < NI; ++i) {
    const int t0 = 2 * i;
    const bool lastI = (i == NI - 1);
    // p1: (buf0,ks0) mh0 | stage tile t0+1 ks1 -> buf1
    PH(0, 0, 0, 1, GUARD_NONE,
       { STG(A1, m0, 1, 0, 1, t0 + 1) STG(Bt, n0, 1, 16384, 1, t0 + 1) })
    // p2: (buf0,ks0) mh1
    PH(0, 1, 0, 0, GUARD_NONE, )
    // p3: (buf0,ks1) mh0 | stage A of tile t0+2 ks0 -> buf0
    PH(0, 0, 1, 1, GUARD_NONE,
       { if (!lastI) { STG(A1, m0, 0, 0, 0, t0 + 2) } })
    // p4: (buf0,ks1) mh1 | stage B of tile t0+2 ks0 | guard
    PH(0, 1, 1, 0, if (lastI) { GUARD0 } else { GUARD4 },
       { if (!lastI) { STG(Bt, n0, 0, 16384, 0, t0 + 2) } })
    // p5: (buf1,ks0) mh0 | stage tile t0+2 ks1 -> buf0
    PH(1, 0, 0, 1, GUARD_NONE,
       { if (!lastI) { STG(A1, m0, 0, 0, 1, t0 + 2)
                       STG(Bt, n0, 0, 16384, 1, t0 + 2) } })
    // p6: (buf1,ks0) mh1
    PH(1, 1, 0, 0, GUARD_NONE, )
    // p7: (buf1,ks1) mh0 | stage A of tile t0+3 ks0 -> buf1
    PH(1, 0, 1, 1, GUARD_NONE,
       { if (!lastI) { STG(A1, m0, 1, 0, 0, t0 + 3) } })
    // p8: (buf1,ks1) mh1 | stage B of tile t0+3 ks0 | guard
    PH(1, 1, 1, 0, if (!lastI) { GUARD4 },
       { if (!lastI) { STG(Bt, n0, 1, 16384, 0, t0 + 3) } })
  }

  // epilogue: C/D layout col=lane&15, row=quad*4+reg
#pragma unroll
  for (int m2 = 0; m2 < 8; ++m2) {
    int row = m0 + wm * 128 + m2 * 16 + quad * 4;
#pragma unroll
    for (int n2 = 0; n2 < 4; ++n2) {
      int col = n0 + wn * 64 + n2 * 16 + lrow;
      float badd = bias ? bias[col] : 0.f;
#pragma unroll
      for (int rr = 0; rr < 4; ++rr) {
        float v = acc[m2][n2][rr] + badd;
        if constexpr (sizeof(OutT) == 4)
          Cout[(size_t)(row + rr) * Ncols + col] = v;
        else
          Cout[(size_t)(row + rr) * Ncols + col] = (OutT)f2bf(v);
      }
    }
  }
}

// ---------------------------------------------------------------------------
// Spatial attention, round-4 restructure. One block per (b,t,h), 7 waves.
// K is NOT LDS-staged (Common-mistake #7: 25 KB K-tile is L1/L2-resident;
// K-frags read straight from global exactly like Q, rows clamped to 195).
// LDS: Vt 29,696 + Ps[7] 51,968 = 81,664 B <= 80 KiB -> 2 blocks/CU
// (3.5 waves/SIMD vs 2 before), and 13 q-tiles over 7 waves = clean 2-pass
// balance (was 2:1 over 8 waves with 119 KB LDS at 1 block/CU).
// Pad handling: S pad cols masked to -inf pre-max (garbage/duplicate K rows
// discarded by assignment); V^T/P pad cols zeroed so 0*garbage != NaN.
// ---------------------------------------------------------------------------
__global__ __launch_bounds__(448) void fsta_spatial(
    const ushort_t* __restrict__ qkv, ushort_t* __restrict__ x1)
{
  __shared__ ushort_t Vt[64 * VS_];        // [dim][key]   29,696 B
  __shared__ ushort_t Ps[7][16 * PS_];     // per-wave P   51,968 B
  const int tid = threadIdx.x;
  const int bid = blockIdx.x;
  const int h   = bid % H_;
  const int bt  = bid / H_;
  const size_t rowbase = (size_t)bt * N_ * C3_;
  const int hofs = h * 64;

  // stage V transposed
  for (int idx = tid; idx < N_ * 8; idx += 448) {
    int n = idx >> 3, c = (idx & 7) * 8;
    size_t so = rowbase + (size_t)n * C3_ + hofs + c + 1536;
    uint4 v = *(const uint4*)(qkv + so);
    ushort_t tmp[8];
    *(uint4*)tmp = v;
#pragma unroll
    for (int i = 0; i < 8; ++i) Vt[(c + i) * VS_ + n] = tmp[i];
  }
  // zero V^T pad cols 196..231
  for (int idx = tid; idx < 64 * (VS_ - N_); idx += 448) {
    int d = idx / (VS_ - N_), k = N_ + idx % (VS_ - N_);
    Vt[d * VS_ + k] = 0;
  }
  __syncthreads();

  const int lane = tid & 63;
  const int wv   = tid >> 6;
  const int lrow = lane & 15;
  const int quad = lane >> 4;
  const int k8   = quad * 8;

  for (int qt = wv; qt < 13; qt += 7) {
    // Q A-frags straight from global (rows clamped; results discarded at store)
    int qrow = qt * 16 + lrow; if (qrow > N_ - 1) qrow = N_ - 1;
    const ushort_t* qp = qkv + rowbase + (size_t)qrow * C3_ + hofs;
    short8 qf0 = *(const short8*)(qp + k8);
    short8 qf1 = *(const short8*)(qp + 32 + k8);

    // S = Q K^T : 13 key tiles, K-dim 64 = 2 MFMA steps; K from global
    floatx4 s[13];
#pragma unroll
    for (int kt = 0; kt < 13; ++kt) {
      int krow = kt * 16 + lrow; if (krow > N_ - 1) krow = N_ - 1;  // folds kt<12
      const ushort_t* kp = qkv + rowbase + (size_t)krow * C3_ + hofs + 768;
      short8 kf0 = *(const short8*)(kp + k8);
      short8 kf1 = *(const short8*)(kp + 32 + k8);
      floatx4 a = (floatx4){0.f, 0.f, 0.f, 0.f};
      a = __builtin_amdgcn_mfma_f32_16x16x32_bf16(qf0, kf0, a, 0, 0, 0);
      a = __builtin_amdgcn_mfma_f32_16x16x32_bf16(qf1, kf1, a, 0, 0, 0);
      s[kt] = a;
    }

    // mask pad cols (tile 12, cols 196..207) before max
    if (lrow >= 4)
      s[12] = (floatx4){-INFINITY, -INFINITY, -INFINITY, -INFINITY};

    // row max + exp + row sum (rows = quad*4+r, cols spread over 16 lanes)
    float mx[4], sum[4];
#pragma unroll
    for (int r = 0; r < 4; ++r) {
      float m2 = s[0][r];
#pragma unroll
      for (int kt = 1; kt < 13; ++kt) m2 = fmaxf(m2, s[kt][r]);
#pragma unroll
      for (int xm = 1; xm < 16; xm <<= 1) m2 = fmaxf(m2, __shfl_xor(m2, xm, 64));
      mx[r] = m2;
    }
#pragma unroll
    for (int r = 0; r < 4; ++r) {
      float sm = 0.f;
#pragma unroll
      for (int kt = 0; kt < 13; ++kt) {
        float p = __expf((s[kt][r] - mx[r]) * 0.125f);   // scale folded in
        s[kt][r] = p;
        sm += p;
      }
#pragma unroll
      for (int xm = 1; xm < 16; xm <<= 1) sm += __shfl_xor(sm, xm, 64);
      sum[r] = sm;
    }

    // P: C/D layout -> LDS (bf16), pad cols 208..223 zeroed
    ushort_t* pw = Ps[wv];
#pragma unroll
    for (int kt = 0; kt < 13; ++kt)
#pragma unroll
      for (int r = 0; r < 4; ++r)
        pw[(quad * 4 + r) * PS_ + kt * 16 + lrow] = f2bf(s[kt][r]);
#pragma unroll
    for (int r = 0; r < 4; ++r)
      pw[(quad * 4 + r) * PS_ + 208 + lrow] = 0;

    // O = P V : A-frag from Ps, B-frag from Vt, 7 k-steps of 32 (224 cols)
    floatx4 o[4];
#pragma unroll
    for (int nt = 0; nt < 4; ++nt) o[nt] = (floatx4){0.f, 0.f, 0.f, 0.f};
#pragma unroll
    for (int kt = 0; kt < 7; ++kt) {
      short8 pf = *(const short8*)&pw[lrow * PS_ + kt * 32 + k8];
#pragma unroll
      for (int nt = 0; nt < 4; ++nt) {
        short8 vf = *(const short8*)&Vt[(nt * 16 + lrow) * VS_ + kt * 32 + k8];
        o[nt] = __builtin_amdgcn_mfma_f32_16x16x32_bf16(pf, vf, o[nt], 0, 0, 0);
      }
    }

    // normalize + store (D rows quad*4+r match sum[r] lanes)
    float inv[4];
#pragma unroll
    for (int r = 0; r < 4; ++r) inv[r] = 1.f / sum[r];
#pragma unroll
    for (int nt = 0; nt < 4; ++nt) {
#pragma unroll
      for (int r = 0; r < 4; ++r) {
        int qr = qt * 16 + quad * 4 + r;
        if (qr < N_)
          x1[(size_t)(bt * N_ + qr) * C_ + hofs + nt * 16 + lrow] =
              f2bf(o[nt][r] * inv[r]);
      }
    }
  }
}

// ---------------------------------------------------------------------------
// Temporal attention, MFMA version. One WAVE per (b,h,n); T=16 rows, hd=64.
// 6 MFMAs/wave + 16-lane shfl softmax; per-wave LDS tiles, no __syncthreads.
// Fuses avg: reads spatial x1 and writes 0.5*(x1+x2) back into same buffer.
// ---------------------------------------------------------------------------
__global__ __launch_bounds__(256) void fsta_temporal(
    const ushort_t* __restrict__ qkv, ushort_t* __restrict__ xavg)
{
  __shared__ ushort_t Pt[4][16 * TS_];   // per-wave P   [t][s]   1,280 B each
  __shared__ ushort_t Vw[4][64 * TS_];   // per-wave V^T [d][s]   5,120 B each
  const int tid  = threadIdx.x;
  const int lane = tid & 63;
  const int wv   = tid >> 6;
  const int gw   = blockIdx.x * 4 + wv;    // global wave id = (b,h,n)
  const int n    = gw % N_;
  const int bh   = gw / N_;
  const int h    = bh % H_;
  const int b    = bh / H_;
  const int hofs = h * 64;
  const int lrow = lane & 15;
  const int quad = lane >> 4;
  const int k8   = quad * 8;

  ushort_t* pw = Pt[wv];
  ushort_t* vw = Vw[wv];

  // zero pad cols s=16..31 of P and V^T (K=32 MFMA step = 16 real + 16 zero)
  for (int i = lane; i < 16 * 16; i += 64)
    pw[(i >> 4) * TS_ + 16 + (i & 15)] = 0;
  for (int i = lane; i < 64 * 16; i += 64)
    vw[(i >> 4) * TS_ + 16 + (i & 15)] = 0;

  // stage V^T: V rows s=0..15 (64 dims) -> vw[d][s]
  for (int i = lane; i < 128; i += 64) {
    int s = i >> 3, c8 = (i & 7) * 8;
    size_t vo = ((size_t)((b * T_ + s) * N_ + n)) * C3_ + hofs + 1536 + c8;
    ushort_t tmp[8];
    *(uint4*)tmp = *(const uint4*)(qkv + vo);
#pragma unroll
    for (int j = 0; j < 8; ++j) vw[(c8 + j) * TS_ + s] = tmp[j];
  }

  // Q (A-frag, row t=lrow) and K (B-frag, row s=lrow) straight from global
  const size_t ro = ((size_t)((b * T_ + lrow) * N_ + n)) * C3_ + hofs;
  short8 qf0 = *(const short8*)(qkv + ro + k8);
  short8 qf1 = *(const short8*)(qkv + ro + 32 + k8);
  short8 kf0 = *(const short8*)(qkv + ro + 768 + k8);
  short8 kf1 = *(const short8*)(qkv + ro + 800 + k8);

  // S = Q K^T : C layout row = quad*4+r (t), col = lrow (s)
  floatx4 s4 = (floatx4){0.f, 0.f, 0.f, 0.f};
  s4 = __builtin_amdgcn_mfma_f32_16x16x32_bf16(qf0, kf0, s4, 0, 0, 0);
  s4 = __builtin_amdgcn_mfma_f32_16x16x32_bf16(qf1, kf1, s4, 0, 0, 0);

  // softmax over the 16 cols (one per lane within the quad group)
  float inv[4];
#pragma unroll
  for (int r = 0; r < 4; ++r) {
    float m2 = s4[r];
#pragma unroll
    for (int xm = 1; xm < 16; xm <<= 1) m2 = fmaxf(m2, __shfl_xor(m2, xm, 64));
    float p = __expf((s4[r] - m2) * 0.125f);   // scale folded in
    float sm = p;
#pragma unroll
    for (int xm = 1; xm < 16; xm <<= 1) sm += __shfl_xor(sm, xm, 64);
    pw[(quad * 4 + r) * TS_ + lrow] = f2bf(p);
    inv[r] = 1.f / sm;
  }

  // O = P V : A-frag from Pt (rows t=lrow), B-frag from Vw; one K=32 step
  short8 pf = *(const short8*)&pw[lrow * TS_ + k8];
  floatx4 o[4];
#pragma unroll
  for (int nt = 0; nt < 4; ++nt) {
    short8 vf = *(const short8*)&vw[(nt * 16 + lrow) * TS_ + k8];
    o[nt] = __builtin_amdgcn_mfma_f32_16x16x32_bf16(
        pf, vf, (floatx4){0.f, 0.f, 0.f, 0.f}, 0, 0, 0);
  }

  // normalize + fused 0.5*(x1+x2): C rows quad*4+r = t, cols nt*16+lrow = d
#pragma unroll
  for (int nt = 0; nt < 4; ++nt)
#pragma unroll
    for (int r = 0; r < 4; ++r) {
      int t = quad * 4 + r;
      size_t xo = ((size_t)((b * T_ + t) * N_ + n)) * C_ + hofs + nt * 16 + lrow;
      float prev = bf2f(xavg[xo]);
      xavg[xo] = f2bf(0.5f * (prev + o[nt][r] * inv[r]));
    }
}

// ---------------------------------------------------------------------------
// ws layout (bf16 elements):
//   WtQkv  @ 0          : 2304*768   = 1,769,472
//   WtProj @ 1,769,472  : 768*768    =   589,824
//   xbf    @ 2,359,296  : 25088*768  = 19,267,584   (aliased as xavg later)
//   qkv    @ 21,626,880 : 25088*2304 = 57,802,752
// total 79,429,632 elems = 158.9 MB
// ---------------------------------------------------------------------------
extern "C" void kernel_launch(void* const* d_in, const int* in_sizes, int n_in,
                              void* d_out, int out_size, void* d_ws, size_t ws_size,
                              hipStream_t stream)
{
  (void)in_sizes; (void)n_in; (void)out_size; (void)ws_size;
  const float* x     = (const float*)d_in[0];
  const float* Wqkv  = (const float*)d_in[1];
  const float* Wproj = (const float*)d_in[2];
  const float* bproj = (const float*)d_in[3];
  float*    out = (float*)d_out;
  ushort_t* ws  = (ushort_t*)d_ws;

  ushort_t* WtQkv  = ws;
  ushort_t* WtProj = ws + 1769472;
  ushort_t* xbf    = ws + 2359296;   // also xavg after spatial
  ushort_t* xavg   = xbf;
  ushort_t* qkv    = ws + 21626880;

  // 1. fused prep: x -> bf16, W_qkv / W_proj -> transposed bf16
  fsta_prep<<<dim3(18624), dim3(256), 0, stream>>>(
      x, xbf, Wqkv, WtQkv, Wproj, WtProj);
  // 2. qkv = x @ W_qkv   : M=25088, N=2304, K=768   (bf16 out, 98x9 tiles)
  fsta_gemm256<ushort_t><<<dim3(98, 9), dim3(512), 0, stream>>>(
      xbf, WtQkv, (const float*)nullptr, qkv, 2304, 768);
  // 3. spatial attention (MFMA, 7 waves, K from global) -> xavg
  fsta_spatial<<<dim3(B_ * T_ * H_), dim3(448), 0, stream>>>(qkv, xavg);
  // 4. temporal attention (MFMA, 1 wave per (b,h,n)), fused 0.5*(x1+x2)
  fsta_temporal<<<dim3((B_ * H_ * N_) / 4), dim3(256), 0, stream>>>(qkv, xavg);
  // 5. out = xavg @ W_proj + b_proj : M=25088, N=768, K=768  (fp32, 98x3 tiles)
  fsta_gemm256<float><<<dim3(98, 3), dim3(512), 0, stream>>>(
      xavg, WtProj, bproj, out, 768, 768);
}

// Round 5
// 416.492 us; speedup vs baseline: 1.0665x; 1.0665x over previous
//
#include <hip/hip_runtime.h>
#include <cstdint>
#include <cstddef>

typedef unsigned short ushort_t;
typedef unsigned int   uint_t;

#define B_   8
#define T_   16
#define N_   196
#define C_   768
#define H_   12
#define C3_  2304
#define M_   25088   // B_*T_*N_

// spatial-attention tiling
#define NP_  208     // N padded to 13 tiles of 16
#define KS_  72      // K LDS row stride (elems): 144 B, 16B-aligned, 2-way alias
#define VS_  232     // V^T LDS row stride: 464 B, 16B-aligned, 2-way alias
#define PS_  232     // P LDS row stride

// temporal-attention tiling
#define TS_  40      // LDS row stride (elems): 80 B, 16B-aligned, 2-way alias

typedef __attribute__((ext_vector_type(8))) short short8;
typedef __attribute__((ext_vector_type(4))) float floatx4;

__device__ __forceinline__ float bf2f(ushort_t u) {
  return __uint_as_float(((uint_t)u) << 16);
}
__device__ __forceinline__ ushort_t f2bf(float f) {
  uint_t u = __float_as_uint(f);
  u += 0x7FFFu + ((u >> 16) & 1u);   // round-to-nearest-even
  return (ushort_t)(u >> 16);
}
__device__ __forceinline__ uint_t pack2(float a, float b) {
  return (uint_t)f2bf(a) | ((uint_t)f2bf(b) << 16);
}

// async global->LDS, 16 B per lane. LDS dest = wave-uniform base + lane*16.
__device__ __forceinline__ void gload_lds16(const ushort_t* g, ushort_t* l) {
  __builtin_amdgcn_global_load_lds(
      (const __attribute__((address_space(1))) uint_t*)g,
      (__attribute__((address_space(3))) uint_t*)l, 16, 0, 0);
}

// raw barrier: compiler memory fence + s_barrier + scheduler pin.
// (NOT __syncthreads(): that drains vmcnt(0) and would kill the counted
// prefetch pipeline.)
__device__ __forceinline__ void bar() {
  asm volatile("" ::: "memory");
  __builtin_amdgcn_s_barrier();
  __builtin_amdgcn_sched_barrier(0);
}

// ---------------------------------------------------------------------------
// Fused prep (one dispatch):
//   blocks [0, 9408)        : x fp32 -> bf16, 8 elems/thread (19,267,584)
//   blocks [9408, 11136)    : W_qkv [768][2304] -> bf16 [2304][768], 32x32
//                             LDS tile transpose (coalesced reads AND writes;
//                             the old strided-9KB fp32 reads fetched 64B/4B)
//   blocks [11136, 11712)   : W_proj [768][768] -> bf16 [768][768], same
// ---------------------------------------------------------------------------
__global__ void fsta_prep(const float* __restrict__ x,
                          ushort_t* __restrict__ xbf,
                          const float* __restrict__ Wqkv,
                          ushort_t* __restrict__ WtQkv,
                          const float* __restrict__ Wproj,
                          ushort_t* __restrict__ WtProj)
{
  __shared__ float tile[32][33];
  const int bid = blockIdx.x;
  const int tid = threadIdx.x;
  if (bid < 9408) {
    int i = (bid * 256 + tid) * 8;
    const float* f = x + i;
    uint4 u;
    u.x = pack2(f[0], f[1]); u.y = pack2(f[2], f[3]);
    u.z = pack2(f[4], f[5]); u.w = pack2(f[6], f[7]);
    *(uint4*)(xbf + i) = u;
    return;
  }
  const float* src; ushort_t* dst; int Cc, rt, ct;
  if (bid < 11136) {
    int b2 = bid - 9408;                 // 1728 blocks = 24 rt x 72 ct
    src = Wqkv; dst = WtQkv; Cc = 2304; ct = b2 % 72; rt = b2 / 72;
  } else {
    int b2 = bid - 11136;                // 576 blocks = 24 x 24
    src = Wproj; dst = WtProj; Cc = 768; ct = b2 % 24; rt = b2 / 24;
  }
  const int tx = tid & 31, ty = tid >> 5;
#pragma unroll
  for (int i = 0; i < 4; ++i)
    tile[ty + i * 8][tx] =
        src[(size_t)(rt * 32 + ty + i * 8) * Cc + ct * 32 + tx];
  __syncthreads();
#pragma unroll
  for (int i = 0; i < 4; ++i)
    dst[(size_t)(ct * 32 + ty + i * 8) * 768 + rt * 32 + tx] =
        f2bf(tile[tx][ty + i * 8]);
}

// ---------------------------------------------------------------------------
// 256x256 8-phase bf16 MFMA GEMM (T1+T2+T3+T4+T5):
//   C[M,N] = A[M,K] @ Bt[N,K]^T (+ fp32 bias)
// 8 waves (2Mx4N), BK=64, per-wave output 128x64, acc[8][4] of 16x16x32.
// LDS 128 KiB = 2 buffers x {A[2 ks-halves][256][32], B[...]}.
// Phase: {ds_read subtile | stage prefetch | (vmcnt guard p4/p8) | barrier |
// 16 MFMA in setprio(1) | barrier}. Counted vmcnt(4): never 0 mid-loop.
// T2 swizzle: chunk c of row r at slot c^((r>>1)&3); verified round 4:
// SQ_LDS_BANK_CONFLICT 8.1M -> 0. FROZEN this round (130 us anchor).
// ---------------------------------------------------------------------------
#define STG(X, rb, bu, xo, kss, t)                                            \
  { _Pragma("unroll") for (int c_ = 0; c_ < 2; ++c_) {                        \
      const ushort_t* g_ = (X) +                                              \
          (size_t)((rb) + c_ * 128 + wv * 16 + srow) * K +                    \
          (t) * 64 + (kss) * 32 + chnk * 8;                                   \
      gload_lds16(g_, &lds[(bu) * 32768 + (xo) + (kss) * 8192 +               \
                           c_ * 4096 + wv * 512]); } }

#define PH(bu, mh, kss, DOB, GUARD, ...)                                      \
  { short8 af[4];                                                             \
    _Pragma("unroll") for (int m2 = 0; m2 < 4; ++m2) {                        \
      int rr = wm * 128 + ((mh) * 4 + m2) * 16 + lrow;                        \
      af[m2] = *(const short8*)&lds[(bu) * 32768 + (kss) * 8192 +             \
                                    rr * 32 + rch8]; }                        \
    if (DOB) {                                                                \
      _Pragma("unroll") for (int n2 = 0; n2 < 4; ++n2) {                      \
        int rr = wn * 64 + n2 * 16 + lrow;                                    \
        bf[n2] = *(const short8*)&lds[(bu) * 32768 + 16384 + (kss) * 8192 +   \
                                      rr * 32 + rch8]; } }                    \
    __VA_ARGS__                                                               \
    GUARD                                                                     \
    bar();                                                                    \
    __builtin_amdgcn_s_setprio(1);                                            \
    _Pragma("unroll") for (int m2 = 0; m2 < 4; ++m2)                          \
      _Pragma("unroll") for (int n2 = 0; n2 < 4; ++n2)                        \
        acc[(mh) * 4 + m2][n2] = __builtin_amdgcn_mfma_f32_16x16x32_bf16(     \
            af[m2], bf[n2], acc[(mh) * 4 + m2][n2], 0, 0, 0);                 \
    __builtin_amdgcn_s_setprio(0);                                            \
    bar(); }

#define GUARD_NONE
#define GUARD4 asm volatile("s_waitcnt vmcnt(4)" ::: "memory");
#define GUARD0 asm volatile("s_waitcnt vmcnt(0)" ::: "memory");

template <typename OutT>
__global__ __launch_bounds__(512) void fsta_gemm256(
    const ushort_t* __restrict__ A1,
    const ushort_t* __restrict__ Bt,
    const float* __restrict__ bias,
    OutT* __restrict__ Cout,
    int Ncols, int K)
{
  __shared__ ushort_t lds[65536];          // 128 KiB
  const int tid  = threadIdx.x;
  const int lane = tid & 63;
  const int wv   = tid >> 6;
  const int wm   = wv >> 2;                // 0..1 (M half)
  const int wn   = wv & 3;                 // 0..3 (N quarter)
  const int lrow = lane & 15;
  const int quad = lane >> 4;
  const int rch8 = (quad ^ ((lrow >> 1) & 3)) * 8;  // swizzled read chunk
  const int srow = lane >> 2;                       // staging row-in-16
  const int chnk = (lane & 3) ^ ((srow >> 1) & 3);  // inverse-swizzled src

  // bijective XCD-chunk swizzle (m204 formula)
  const int ntx = gridDim.x;
  const int nwg = ntx * gridDim.y;
  int lin = blockIdx.y * ntx + blockIdx.x;
  {
    int q = nwg >> 3, r = nwg & 7;
    int xcd = lin & 7, off = lin >> 3;
    lin = (xcd < r ? xcd * (q + 1) : r * (q + 1) + (xcd - r) * q) + off;
  }
  const int m0 = (lin % ntx) * 256;
  const int n0 = (lin / ntx) * 256;

  const int NT = K >> 6;                   // 64-wide K-tiles (12)
  const int NI = NT >> 1;                  // iterations (6)

  floatx4 acc[8][4];
#pragma unroll
  for (int i = 0; i < 8; ++i)
#pragma unroll
    for (int j = 0; j < 4; ++j)
      acc[i][j] = (floatx4){0.f, 0.f, 0.f, 0.f};

  // prologue: tile0 (both ks halves) + tile1 ks0; leave tile1-ks0 in flight
  STG(A1, m0, 0, 0,     0, 0)
  STG(Bt, n0, 0, 16384, 0, 0)
  STG(A1, m0, 0, 0,     1, 0)
  STG(Bt, n0, 0, 16384, 1, 0)
  STG(A1, m0, 1, 0,     0, 1)
  STG(Bt, n0, 1, 16384, 0, 1)
  GUARD4                                   // tile0 fully landed
  bar();

  short8 bf[4];                            // B-frags persist across mh phases
  for (int i = 0; i < NI; ++i) {
    const int t0 = 2 * i;
    const bool lastI = (i == NI - 1);
    // p1: (buf0,ks0) mh0 | stage tile t0+1 ks1 -> buf1
    PH(0, 0, 0, 1, GUARD_NONE,
       { STG(A1, m0, 1, 0, 1, t0 + 1) STG(Bt, n0, 1, 16384, 1, t0 + 1) })
    // p2: (buf0,ks0) mh1
    PH(0, 1, 0, 0, GUARD_NONE, )
    // p3: (buf0,ks1) mh0 | stage A of tile t0+2 ks0 -> buf0
    PH(0, 0, 1, 1, GUARD_NONE,
       { if (!lastI) { STG(A1, m0, 0, 0, 0, t0 + 2) } })
    // p4: (buf0,ks1) mh1 | stage B of tile t0+2 ks0 | guard
    PH(0, 1, 1, 0, if (lastI) { GUARD0 } else { GUARD4 },
       { if (!lastI) { STG(Bt, n0, 0, 16384, 0, t0 + 2) } })
    // p5: (buf1,ks0) mh0 | stage tile t0+2 ks1 -> buf0
    PH(1, 0, 0, 1, GUARD_NONE,
       { if (!lastI) { STG(A1, m0, 0, 0, 1, t0 + 2)
                       STG(Bt, n0, 0, 16384, 1, t0 + 2) } })
    // p6: (buf1,ks0) mh1
    PH(1, 1, 0, 0, GUARD_NONE, )
    // p7: (buf1,ks1) mh0 | stage A of tile t0+3 ks0 -> buf1
    PH(1, 0, 1, 1, GUARD_NONE,
       { if (!lastI) { STG(A1, m0, 1, 0, 0, t0 + 3) } })
    // p8: (buf1,ks1) mh1 | stage B of tile t0+3 ks0 | guard
    PH(1, 1, 1, 0, if (!lastI) { GUARD4 },
       { if (!lastI) { STG(Bt, n0, 1, 16384, 0, t0 + 3) } })
  }

  // epilogue: C/D layout col=lane&15, row=quad*4+reg
#pragma unroll
  for (int m2 = 0; m2 < 8; ++m2) {
    int row = m0 + wm * 128 + m2 * 16 + quad * 4;
#pragma unroll
    for (int n2 = 0; n2 < 4; ++n2) {
      int col = n0 + wn * 64 + n2 * 16 + lrow;
      float badd = bias ? bias[col] : 0.f;
#pragma unroll
      for (int rr = 0; rr < 4; ++rr) {
        float v = acc[m2][n2][rr] + badd;
        if constexpr (sizeof(OutT) == 4)
          Cout[(size_t)(row + rr) * Ncols + col] = v;
        else
          Cout[(size_t)(row + rr) * Ncols + col] = (OutT)f2bf(v);
      }
    }
  }
}

// ---------------------------------------------------------------------------
// Spatial attention. REVERTED to the round-3 structure (K staged in LDS —
// the K-from-global variant regressed ~25 us: L2-latency-exposed serial
// K-frag loads) + NEW coalesced epilogue: O staged to a wave-private LDS
// [16][64] tile, then rows written as 128 B contiguous stores (was 16
// scattered 32 B quad-stores).
// One block per (b,t,h), 8 waves. LDS: Ks 29.9K + Vt 29.7K + Ps 59.4K +
// Os 16.4K = 135.4 KB -> 1 block/CU, 2 waves/SIMD.
// ---------------------------------------------------------------------------
__global__ __launch_bounds__(512) void fsta_spatial(
    const ushort_t* __restrict__ qkv, ushort_t* __restrict__ x1)
{
  __shared__ ushort_t Ks[NP_ * KS_];       // [key][dim]   29,952 B
  __shared__ ushort_t Vt[64 * VS_];        // [dim][key]   29,696 B
  __shared__ ushort_t Ps[8][16 * PS_];     // per-wave P   59,392 B
  __shared__ ushort_t Os[8][16 * 64];      // per-wave O   16,384 B
  const int tid = threadIdx.x;
  const int bid = blockIdx.x;
  const int h   = bid % H_;
  const int bt  = bid / H_;
  const size_t rowbase = (size_t)bt * N_ * C3_;
  const int hofs = h * 64;

  // stage K row-major and V transposed
  for (int idx = tid; idx < N_ * 8; idx += 512) {
    int n = idx >> 3, c = (idx & 7) * 8;
    size_t so = rowbase + (size_t)n * C3_ + hofs + c;
    *(uint4*)&Ks[n * KS_ + c] = *(const uint4*)(qkv + so + 768);
    uint4 v = *(const uint4*)(qkv + so + 1536);
    ushort_t tmp[8];
    *(uint4*)tmp = v;
#pragma unroll
    for (int i = 0; i < 8; ++i) Vt[(c + i) * VS_ + n] = tmp[i];
  }
  // zero V^T pad cols 196..231
  for (int idx = tid; idx < 64 * (VS_ - N_); idx += 512) {
    int d = idx / (VS_ - N_), k = N_ + idx % (VS_ - N_);
    Vt[d * VS_ + k] = 0;
  }
  __syncthreads();

  const int lane = tid & 63;
  const int wv   = tid >> 6;
  const int lrow = lane & 15;
  const int quad = lane >> 4;
  const int k8   = quad * 8;

  for (int qt = wv; qt < 13; qt += 8) {
    // Q A-frags straight from global (rows clamped; results discarded at store)
    int qrow = qt * 16 + lrow; if (qrow > N_ - 1) qrow = N_ - 1;
    const ushort_t* qp = qkv + rowbase + (size_t)qrow * C3_ + hofs;
    short8 qf0 = *(const short8*)(qp + k8);
    short8 qf1 = *(const short8*)(qp + 32 + k8);

    // S = Q K^T : 13 key tiles, K-dim 64 = 2 MFMA steps
    floatx4 s[13];
#pragma unroll
    for (int kt = 0; kt < 13; ++kt) {
      const ushort_t* kp = &Ks[(kt * 16 + lrow) * KS_];
      short8 kf0 = *(const short8*)(kp + k8);
      short8 kf1 = *(const short8*)(kp + 32 + k8);
      floatx4 a = (floatx4){0.f, 0.f, 0.f, 0.f};
      a = __builtin_amdgcn_mfma_f32_16x16x32_bf16(qf0, kf0, a, 0, 0, 0);
      a = __builtin_amdgcn_mfma_f32_16x16x32_bf16(qf1, kf1, a, 0, 0, 0);
      s[kt] = a;
    }

    // mask pad cols (tile 12, cols 196..207) before max
    if (lrow >= 4)
      s[12] = (floatx4){-INFINITY, -INFINITY, -INFINITY, -INFINITY};

    // row max + exp + row sum (rows = quad*4+r, cols spread over 16 lanes)
    float mx[4], sum[4];
#pragma unroll
    for (int r = 0; r < 4; ++r) {
      float m2 = s[0][r];
#pragma unroll
      for (int kt = 1; kt < 13; ++kt) m2 = fmaxf(m2, s[kt][r]);
#pragma unroll
      for (int xm = 1; xm < 16; xm <<= 1) m2 = fmaxf(m2, __shfl_xor(m2, xm, 64));
      mx[r] = m2;
    }
#pragma unroll
    for (int r = 0; r < 4; ++r) {
      float sm = 0.f;
#pragma unroll
      for (int kt = 0; kt < 13; ++kt) {
        float p = __expf((s[kt][r] - mx[r]) * 0.125f);   // scale folded in
        s[kt][r] = p;
        sm += p;
      }
#pragma unroll
      for (int xm = 1; xm < 16; xm <<= 1) sm += __shfl_xor(sm, xm, 64);
      sum[r] = sm;
    }

    // P: C/D layout -> LDS (bf16), pad cols 208..223 zeroed
    ushort_t* pw = Ps[wv];
#pragma unroll
    for (int kt = 0; kt < 13; ++kt)
#pragma unroll
      for (int r = 0; r < 4; ++r)
        pw[(quad * 4 + r) * PS_ + kt * 16 + lrow] = f2bf(s[kt][r]);
#pragma unroll
    for (int r = 0; r < 4; ++r)
      pw[(quad * 4 + r) * PS_ + 208 + lrow] = 0;

    // O = P V : A-frag from Ps, B-frag from Vt, 7 k-steps of 32 (224 cols)
    floatx4 o[4];
#pragma unroll
    for (int nt = 0; nt < 4; ++nt) o[nt] = (floatx4){0.f, 0.f, 0.f, 0.f};
#pragma unroll
    for (int kt = 0; kt < 7; ++kt) {
      short8 pf = *(const short8*)&pw[lrow * PS_ + kt * 32 + k8];
#pragma unroll
      for (int nt = 0; nt < 4; ++nt) {
        short8 vf = *(const short8*)&Vt[(nt * 16 + lrow) * VS_ + kt * 32 + k8];
        o[nt] = __builtin_amdgcn_mfma_f32_16x16x32_bf16(pf, vf, o[nt], 0, 0, 0);
      }
    }

    // normalize, stage to wave-private LDS [row][d], write coalesced rows
    float inv[4];
#pragma unroll
    for (int r = 0; r < 4; ++r) inv[r] = 1.f / sum[r];
    ushort_t* ow = Os[wv];
#pragma unroll
    for (int nt = 0; nt < 4; ++nt)
#pragma unroll
      for (int r = 0; r < 4; ++r)
        ow[(quad * 4 + r) * 64 + nt * 16 + lrow] = f2bf(o[nt][r] * inv[r]);
#pragma unroll
    for (int tr = 0; tr < 16; ++tr) {
      int qr = qt * 16 + tr;
      if (qr < N_)
        x1[(size_t)(bt * N_ + qr) * C_ + hofs + lane] = ow[tr * 64 + lane];
    }
  }
}

// ---------------------------------------------------------------------------
// Temporal attention. One WAVE per (b,h,n); T=16 rows, hd=64. 6 MFMAs/wave
// + 16-lane shfl softmax; per-wave LDS tiles, no __syncthreads.
// NEW: fused avg 0.5*(x1+x2) now goes through a wave-private LDS [16][64]
// O-tile so the global read-modify-write is 16 rows of 128 B contiguous
// (was 32 scattered 32 B quad accesses over 77 MB of traffic).
// LDS/block: Pt 5.1K + Vw 20.5K + Ot 8.2K = 33.8 KB -> 4 blocks/CU.
// ---------------------------------------------------------------------------
__global__ __launch_bounds__(256) void fsta_temporal(
    const ushort_t* __restrict__ qkv, ushort_t* __restrict__ xavg)
{
  __shared__ ushort_t Pt[4][16 * TS_];   // per-wave P   [t][s]   1,280 B each
  __shared__ ushort_t Vw[4][64 * TS_];   // per-wave V^T [d][s]   5,120 B each
  __shared__ ushort_t Ot[4][16 * 64];    // per-wave O   [t][d]   2,048 B each
  const int tid  = threadIdx.x;
  const int lane = tid & 63;
  const int wv   = tid >> 6;
  const int gw   = blockIdx.x * 4 + wv;    // global wave id = (b,h,n)
  const int n    = gw % N_;
  const int bh   = gw / N_;
  const int h    = bh % H_;
  const int b    = bh / H_;
  const int hofs = h * 64;
  const int lrow = lane & 15;
  const int quad = lane >> 4;
  const int k8   = quad * 8;

  ushort_t* pw = Pt[wv];
  ushort_t* vw = Vw[wv];

  // zero pad cols s=16..31 of P and V^T (K=32 MFMA step = 16 real + 16 zero)
  for (int i = lane; i < 16 * 16; i += 64)
    pw[(i >> 4) * TS_ + 16 + (i & 15)] = 0;
  for (int i = lane; i < 64 * 16; i += 64)
    vw[(i >> 4) * TS_ + 16 + (i & 15)] = 0;

  // stage V^T: V rows s=0..15 (64 dims) -> vw[d][s]
  for (int i = lane; i < 128; i += 64) {
    int s = i >> 3, c8 = (i & 7) * 8;
    size_t vo = ((size_t)((b * T_ + s) * N_ + n)) * C3_ + hofs + 1536 + c8;
    ushort_t tmp[8];
    *(uint4*)tmp = *(const uint4*)(qkv + vo);
#pragma unroll
    for (int j = 0; j < 8; ++j) vw[(c8 + j) * TS_ + s] = tmp[j];
  }

  // Q (A-frag, row t=lrow) and K (B-frag, row s=lrow) straight from global
  const size_t ro = ((size_t)((b * T_ + lrow) * N_ + n)) * C3_ + hofs;
  short8 qf0 = *(const short8*)(qkv + ro + k8);
  short8 qf1 = *(const short8*)(qkv + ro + 32 + k8);
  short8 kf0 = *(const short8*)(qkv + ro + 768 + k8);
  short8 kf1 = *(const short8*)(qkv + ro + 800 + k8);

  // S = Q K^T : C layout row = quad*4+r (t), col = lrow (s)
  floatx4 s4 = (floatx4){0.f, 0.f, 0.f, 0.f};
  s4 = __builtin_amdgcn_mfma_f32_16x16x32_bf16(qf0, kf0, s4, 0, 0, 0);
  s4 = __builtin_amdgcn_mfma_f32_16x16x32_bf16(qf1, kf1, s4, 0, 0, 0);

  // softmax over the 16 cols (one per lane within the quad group)
  float inv[4];
#pragma unroll
  for (int r = 0; r < 4; ++r) {
    float m2 = s4[r];
#pragma unroll
    for (int xm = 1; xm < 16; xm <<= 1) m2 = fmaxf(m2, __shfl_xor(m2, xm, 64));
    float p = __expf((s4[r] - m2) * 0.125f);   // scale folded in
    float sm = p;
#pragma unroll
    for (int xm = 1; xm < 16; xm <<= 1) sm += __shfl_xor(sm, xm, 64);
    pw[(quad * 4 + r) * TS_ + lrow] = f2bf(p);
    inv[r] = 1.f / sm;
  }

  // O = P V : A-frag from Pt (rows t=lrow), B-frag from Vw; one K=32 step
  short8 pf = *(const short8*)&pw[lrow * TS_ + k8];
  floatx4 o[4];
#pragma unroll
  for (int nt = 0; nt < 4; ++nt) {
    short8 vf = *(const short8*)&vw[(nt * 16 + lrow) * TS_ + k8];
    o[nt] = __builtin_amdgcn_mfma_f32_16x16x32_bf16(
        pf, vf, (floatx4){0.f, 0.f, 0.f, 0.f}, 0, 0, 0);
  }

  // stage normalized O to wave-private LDS [t][d]
  ushort_t* ow = Ot[wv];
#pragma unroll
  for (int nt = 0; nt < 4; ++nt)
#pragma unroll
    for (int r = 0; r < 4; ++r)
      ow[(quad * 4 + r) * 64 + nt * 16 + lrow] = f2bf(o[nt][r] * inv[r]);

  // fused 0.5*(x1+x2): row t = 64 lanes x 2B = 128 B contiguous RMW
  const size_t obase = ((size_t)(b * T_) * N_ + n) * C_ + hofs + lane;
#pragma unroll
  for (int t = 0; t < T_; ++t) {
    size_t xo = obase + (size_t)t * (N_ * C_);
    float prev = bf2f(xavg[xo]);
    xavg[xo] = f2bf(0.5f * (prev + bf2f(ow[t * 64 + lane])));
  }
}

// ---------------------------------------------------------------------------
// ws layout (bf16 elements):
//   WtQkv  @ 0          : 2304*768   = 1,769,472
//   WtProj @ 1,769,472  : 768*768    =   589,824
//   xbf    @ 2,359,296  : 25088*768  = 19,267,584   (aliased as xavg later)
//   qkv    @ 21,626,880 : 25088*2304 = 57,802,752
// total 79,429,632 elems = 158.9 MB
// ---------------------------------------------------------------------------
extern "C" void kernel_launch(void* const* d_in, const int* in_sizes, int n_in,
                              void* d_out, int out_size, void* d_ws, size_t ws_size,
                              hipStream_t stream)
{
  (void)in_sizes; (void)n_in; (void)out_size; (void)ws_size;
  const float* x     = (const float*)d_in[0];
  const float* Wqkv  = (const float*)d_in[1];
  const float* Wproj = (const float*)d_in[2];
  const float* bproj = (const float*)d_in[3];
  float*    out = (float*)d_out;
  ushort_t* ws  = (ushort_t*)d_ws;

  ushort_t* WtQkv  = ws;
  ushort_t* WtProj = ws + 1769472;
  ushort_t* xbf    = ws + 2359296;   // also xavg after spatial
  ushort_t* xavg   = xbf;
  ushort_t* qkv    = ws + 21626880;

  // 1. fused prep: x -> bf16, W_qkv / W_proj -> transposed bf16 (LDS tiles)
  fsta_prep<<<dim3(11712), dim3(256), 0, stream>>>(
      x, xbf, Wqkv, WtQkv, Wproj, WtProj);
  // 2. qkv = x @ W_qkv   : M=25088, N=2304, K=768   (bf16 out, 98x9 tiles)
  fsta_gemm256<ushort_t><<<dim3(98, 9), dim3(512), 0, stream>>>(
      xbf, WtQkv, (const float*)nullptr, qkv, 2304, 768);
  // 3. spatial attention (MFMA, 8 waves, K in LDS) -> xavg
  fsta_spatial<<<dim3(B_ * T_ * H_), dim3(512), 0, stream>>>(qkv, xavg);
  // 4. temporal attention (MFMA, 1 wave per (b,h,n)), fused 0.5*(x1+x2)
  fsta_temporal<<<dim3((B_ * H_ * N_) / 4), dim3(256), 0, stream>>>(qkv, xavg);
  // 5. out = xavg @ W_proj + b_proj : M=25088, N=768, K=768  (fp32, 98x3 tiles)
  fsta_gemm256<float><<<dim3(98, 3), dim3(512), 0, stream>>>(
      xavg, WtProj, bproj, out, 768, 768);
}

// Round 8
// 394.833 us; speedup vs baseline: 1.1250x; 1.0549x over previous
//
#include <hip/hip_runtime.h>
#include <cstdint>
#include <cstddef>

typedef unsigned short ushort_t;
typedef unsigned int   uint_t;

#define B_   8
#define T_   16
#define N_   196
#define C_   768
#define H_   12
#define C3_  2304
#define M_   25088   // B_*T_*N_

// spatial-attention tiling
#define NP_  208     // N padded to 13 tiles of 16
#define KS_  72      // K LDS row stride (elems): 144 B, 16B-aligned, 2-way alias
#define VS_  232     // V^T LDS row stride: 464 B, 16B-aligned, 2-way alias
#define PS_  232     // P LDS row stride

// temporal-attention tiling
#define TS_  40      // LDS row stride (elems): 80 B, 16B-aligned, 2-way alias

typedef __attribute__((ext_vector_type(8))) short short8;
typedef __attribute__((ext_vector_type(4))) float floatx4;

__device__ __forceinline__ float bf2f(ushort_t u) {
  return __uint_as_float(((uint_t)u) << 16);
}
__device__ __forceinline__ ushort_t f2bf(float f) {
  uint_t u = __float_as_uint(f);
  u += 0x7FFFu + ((u >> 16) & 1u);   // round-to-nearest-even
  return (ushort_t)(u >> 16);
}
__device__ __forceinline__ uint_t pack2(float a, float b) {
  return (uint_t)f2bf(a) | ((uint_t)f2bf(b) << 16);
}

// async global->LDS, 16 B per lane. LDS dest = wave-uniform base + lane*16.
__device__ __forceinline__ void gload_lds16(const ushort_t* g, ushort_t* l) {
  __builtin_amdgcn_global_load_lds(
      (const __attribute__((address_space(1))) uint_t*)g,
      (__attribute__((address_space(3))) uint_t*)l, 16, 0, 0);
}

// raw barrier: compiler memory fence + s_barrier + scheduler pin.
// (NOT __syncthreads(): that drains vmcnt(0) and would kill the counted
// prefetch pipeline.)
__device__ __forceinline__ void bar() {
  asm volatile("" ::: "memory");
  __builtin_amdgcn_s_barrier();
  __builtin_amdgcn_sched_barrier(0);
}

// ---------------------------------------------------------------------------
// Fused prep (one dispatch):
//   blocks [0, 9408)        : x fp32 -> bf16, 8 elems/thread (19,267,584)
//   blocks [9408, 11136)    : W_qkv [768][2304] -> bf16 [2304][768], 32x32
//                             LDS tile transpose (coalesced reads AND writes)
//   blocks [11136, 11712)   : W_proj [768][768] -> bf16 [768][768], same
// ---------------------------------------------------------------------------
__global__ void fsta_prep(const float* __restrict__ x,
                          ushort_t* __restrict__ xbf,
                          const float* __restrict__ Wqkv,
                          ushort_t* __restrict__ WtQkv,
                          const float* __restrict__ Wproj,
                          ushort_t* __restrict__ WtProj)
{
  __shared__ float tile[32][33];
  const int bid = blockIdx.x;
  const int tid = threadIdx.x;
  if (bid < 9408) {
    int i = (bid * 256 + tid) * 8;
    const float* f = x + i;
    uint4 u;
    u.x = pack2(f[0], f[1]); u.y = pack2(f[2], f[3]);
    u.z = pack2(f[4], f[5]); u.w = pack2(f[6], f[7]);
    *(uint4*)(xbf + i) = u;
    return;
  }
  const float* src; ushort_t* dst; int Cc, rt, ct;
  if (bid < 11136) {
    int b2 = bid - 9408;                 // 1728 blocks = 24 rt x 72 ct
    src = Wqkv; dst = WtQkv; Cc = 2304; ct = b2 % 72; rt = b2 / 72;
  } else {
    int b2 = bid - 11136;                // 576 blocks = 24 x 24
    src = Wproj; dst = WtProj; Cc = 768; ct = b2 % 24; rt = b2 / 24;
  }
  const int tx = tid & 31, ty = tid >> 5;
#pragma unroll
  for (int i = 0; i < 4; ++i)
    tile[ty + i * 8][tx] =
        src[(size_t)(rt * 32 + ty + i * 8) * Cc + ct * 32 + tx];
  __syncthreads();
#pragma unroll
  for (int i = 0; i < 4; ++i)
    dst[(size_t)(ct * 32 + ty + i * 8) * 768 + rt * 32 + tx] =
        f2bf(tile[tx][ty + i * 8]);
}

// ---------------------------------------------------------------------------
// 256x256 8-phase bf16 MFMA GEMM (T1+T2+T3+T4+T5):
//   C[M,N] = A[M,K] @ Bt[N,K]^T (+ fp32 bias)
// 8 waves (2Mx4N), BK=64, per-wave output 128x64, acc[8][4] of 16x16x32.
// Phase: {ds_read subtile | stage prefetch | (vmcnt guard p4/p8) | barrier |
// 16 MFMA in setprio(1) | barrier}. Counted vmcnt(4): never 0 mid-loop.
// T2 swizzle verified round 4: SQ_LDS_BANK_CONFLICT 8.1M -> 0.
//
// ROUND-6 FIX (counter-driven): lin->tile mapping was n-outer/m-inner, so an
// XCD's contiguous chunk iterated ALL 98 M-tiles at one n -> the 38.5 MB A
// panel streamed through the 4 MB L2 once per n column (FETCH_SIZE 177 MB =
// 4.2x ideal). Now n-INNER: lin/gdy = m-tile, lin%gdy = n-tile; per-XCD
// working set = one 0.39 MB A-panel (reused across all n) + 3.5 MB B ~= L2.
// Predicted FETCH -> ~80 MB.
// ---------------------------------------------------------------------------
#define STG(X, rb, bu, xo, kss, t)                                            \
  { _Pragma("unroll") for (int c_ = 0; c_ < 2; ++c_) {                        \
      const ushort_t* g_ = (X) +                                              \
          (size_t)((rb) + c_ * 128 + wv * 16 + srow) * K +                    \
          (t) * 64 + (kss) * 32 + chnk * 8;                                   \
      gload_lds16(g_, &lds[(bu) * 32768 + (xo) + (kss) * 8192 +               \
                           c_ * 4096 + wv * 512]); } }

#define PH(bu, mh, kss, DOB, GUARD, ...)                                      \
  { short8 af[4];                                                             \
    _Pragma("unroll") for (int m2 = 0; m2 < 4; ++m2) {                        \
      int rr = wm * 128 + ((mh) * 4 + m2) * 16 + lrow;                        \
      af[m2] = *(const short8*)&lds[(bu) * 32768 + (kss) * 8192 +             \
                                    rr * 32 + rch8]; }                        \
    if (DOB) {                                                                \
      _Pragma("unroll") for (int n2 = 0; n2 < 4; ++n2) {                      \
        int rr = wn * 64 + n2 * 16 + lrow;                                    \
        bf[n2] = *(const short8*)&lds[(bu) * 32768 + 16384 + (kss) * 8192 +   \
                                      rr * 32 + rch8]; } }                    \
    __VA_ARGS__                                                               \
    GUARD                                                                     \
    bar();                                                                    \
    __builtin_amdgcn_s_setprio(1);                                            \
    _Pragma("unroll") for (int m2 = 0; m2 < 4; ++m2)                          \
      _Pragma("unroll") for (int n2 = 0; n2 < 4; ++n2)                        \
        acc[(mh) * 4 + m2][n2] = __builtin_amdgcn_mfma_f32_16x16x32_bf16(     \
            af[m2], bf[n2], acc[(mh) * 4 + m2][n2], 0, 0, 0);                 \
    __builtin_amdgcn_s_setprio(0);                                            \
    bar(); }

#define GUARD_NONE
#define GUARD4 asm volatile("s_waitcnt vmcnt(4)" ::: "memory");
#define GUARD0 asm volatile("s_waitcnt vmcnt(0)" ::: "memory");

template <typename OutT>
__global__ __launch_bounds__(512) void fsta_gemm256(
    const ushort_t* __restrict__ A1,
    const ushort_t* __restrict__ Bt,
    const float* __restrict__ bias,
    OutT* __restrict__ Cout,
    int Ncols, int K)
{
  __shared__ ushort_t lds[65536];          // 128 KiB
  const int tid  = threadIdx.x;
  const int lane = tid & 63;
  const int wv   = tid >> 6;
  const int wm   = wv >> 2;                // 0..1 (M half)
  const int wn   = wv & 3;                 // 0..3 (N quarter)
  const int lrow = lane & 15;
  const int quad = lane >> 4;
  const int rch8 = (quad ^ ((lrow >> 1) & 3)) * 8;  // swizzled read chunk
  const int srow = lane >> 2;                       // staging row-in-16
  const int chnk = (lane & 3) ^ ((srow >> 1) & 3);  // inverse-swizzled src

  // bijective XCD-chunk swizzle (m204 formula)
  const int ntx = gridDim.x;
  const int gdy = gridDim.y;
  const int nwg = ntx * gdy;
  int lin = blockIdx.y * ntx + blockIdx.x;
  {
    int q = nwg >> 3, r = nwg & 7;
    int xcd = lin & 7, off = lin >> 3;
    lin = (xcd < r ? xcd * (q + 1) : r * (q + 1) + (xcd - r) * q) + off;
  }
  // n-INNER tile order: consecutive lin share the A-panel (L2-resident)
  const int m0 = (lin / gdy) * 256;
  const int n0 = (lin % gdy) * 256;

  const int NT = K >> 6;                   // 64-wide K-tiles (12)
  const int NI = NT >> 1;                  // iterations (6)

  floatx4 acc[8][4];
#pragma unroll
  for (int i = 0; i < 8; ++i)
#pragma unroll
    for (int j = 0; j < 4; ++j)
      acc[i][j] = (floatx4){0.f, 0.f, 0.f, 0.f};

  // prologue: tile0 (both ks halves) + tile1 ks0; leave tile1-ks0 in flight
  STG(A1, m0, 0, 0,     0, 0)
  STG(Bt, n0, 0, 16384, 0, 0)
  STG(A1, m0, 0, 0,     1, 0)
  STG(Bt, n0, 0, 16384, 1, 0)
  STG(A1, m0, 1, 0,     0, 1)
  STG(Bt, n0, 1, 16384, 0, 1)
  GUARD4                                   // tile0 fully landed
  bar();

  short8 bf[4];                            // B-frags persist across mh phases
  for (int i = 0; i < NI; ++i) {
    const int t0 = 2 * i;
    const bool lastI = (i == NI - 1);
    // p1: (buf0,ks0) mh0 | stage tile t0+1 ks1 -> buf1
    PH(0, 0, 0, 1, GUARD_NONE,
       { STG(A1, m0, 1, 0, 1, t0 + 1) STG(Bt, n0, 1, 16384, 1, t0 + 1) })
    // p2: (buf0,ks0) mh1
    PH(0, 1, 0, 0, GUARD_NONE, )
    // p3: (buf0,ks1) mh0 | stage A of tile t0+2 ks0 -> buf0
    PH(0, 0, 1, 1, GUARD_NONE,
       { if (!lastI) { STG(A1, m0, 0, 0, 0, t0 + 2) } })
    // p4: (buf0,ks1) mh1 | stage B of tile t0+2 ks0 | guard
    PH(0, 1, 1, 0, if (lastI) { GUARD0 } else { GUARD4 },
       { if (!lastI) { STG(Bt, n0, 0, 16384, 0, t0 + 2) } })
    // p5: (buf1,ks0) mh0 | stage tile t0+2 ks1 -> buf0
    PH(1, 0, 0, 1, GUARD_NONE,
       { if (!lastI) { STG(A1, m0, 0, 0, 1, t0 + 2)
                       STG(Bt, n0, 0, 16384, 1, t0 + 2) } })
    // p6: (buf1,ks0) mh1
    PH(1, 1, 0, 0, GUARD_NONE, )
    // p7: (buf1,ks1) mh0 | stage A of tile t0+3 ks0 -> buf1
    PH(1, 0, 1, 1, GUARD_NONE,
       { if (!lastI) { STG(A1, m0, 1, 0, 0, t0 + 3) } })
    // p8: (buf1,ks1) mh1 | stage B of tile t0+3 ks0 | guard
    PH(1, 1, 1, 0, if (!lastI) { GUARD4 },
       { if (!lastI) { STG(Bt, n0, 1, 16384, 0, t0 + 3) } })
  }

  // epilogue: C/D layout col=lane&15, row=quad*4+reg
#pragma unroll
  for (int m2 = 0; m2 < 8; ++m2) {
    int row = m0 + wm * 128 + m2 * 16 + quad * 4;
#pragma unroll
    for (int n2 = 0; n2 < 4; ++n2) {
      int col = n0 + wn * 64 + n2 * 16 + lrow;
      float badd = bias ? bias[col] : 0.f;
#pragma unroll
      for (int rr = 0; rr < 4; ++rr) {
        float v = acc[m2][n2][rr] + badd;
        if constexpr (sizeof(OutT) == 4)
          Cout[(size_t)(row + rr) * Ncols + col] = v;
        else
          Cout[(size_t)(row + rr) * Ncols + col] = (OutT)f2bf(v);
      }
    }
  }
}

// ---------------------------------------------------------------------------
// Spatial attention: 13 waves (832 threads), exactly ONE q-tile per wave.
// (Round-5 had 13 tiles over 8 waves -> 5 waves did 2 serial tiles at only
// 2 waves/SIMD; now block time = 1 tile at 3-4 waves/SIMD, perfectly flat.)
// LDS: Ks 29,952 + Vt 29,696 + Ps[13] 96,512 = 156,160 B <= 160 KiB.
// O reuses the (dead) P region for the coalesced 128 B-row epilogue.
// Single __syncthreads (after staging) executed by all 832 threads.
// ---------------------------------------------------------------------------
__global__ __launch_bounds__(832) void fsta_spatial(
    const ushort_t* __restrict__ qkv, ushort_t* __restrict__ x1)
{
  __shared__ ushort_t Ks[NP_ * KS_];       // [key][dim]   29,952 B
  __shared__ ushort_t Vt[64 * VS_];        // [dim][key]   29,696 B
  __shared__ ushort_t Ps[13][16 * PS_];    // per-wave P   96,512 B
  const int tid = threadIdx.x;
  const int bid = blockIdx.x;
  const int h   = bid % H_;
  const int bt  = bid / H_;
  const size_t rowbase = (size_t)bt * N_ * C3_;
  const int hofs = h * 64;

  // stage K row-major and V transposed
  for (int idx = tid; idx < N_ * 8; idx += 832) {
    int n = idx >> 3, c = (idx & 7) * 8;
    size_t so = rowbase + (size_t)n * C3_ + hofs + c;
    *(uint4*)&Ks[n * KS_ + c] = *(const uint4*)(qkv + so + 768);
    uint4 v = *(const uint4*)(qkv + so + 1536);
    ushort_t tmp[8];
    *(uint4*)tmp = v;
#pragma unroll
    for (int i = 0; i < 8; ++i) Vt[(c + i) * VS_ + n] = tmp[i];
  }
  // zero V^T pad cols 196..231
  for (int idx = tid; idx < 64 * (VS_ - N_); idx += 832) {
    int d = idx / (VS_ - N_), k = N_ + idx % (VS_ - N_);
    Vt[d * VS_ + k] = 0;
  }
  __syncthreads();

  const int lane = tid & 63;
  const int qt   = tid >> 6;               // wave id == q-tile id, 0..12
  const int lrow = lane & 15;
  const int quad = lane >> 4;
  const int k8   = quad * 8;

  {
    // Q A-frags straight from global (rows clamped; results discarded at store)
    int qrow = qt * 16 + lrow; if (qrow > N_ - 1) qrow = N_ - 1;
    const ushort_t* qp = qkv + rowbase + (size_t)qrow * C3_ + hofs;
    short8 qf0 = *(const short8*)(qp + k8);
    short8 qf1 = *(const short8*)(qp + 32 + k8);

    // S = Q K^T : 13 key tiles, K-dim 64 = 2 MFMA steps
    floatx4 s[13];
#pragma unroll
    for (int kt = 0; kt < 13; ++kt) {
      const ushort_t* kp = &Ks[(kt * 16 + lrow) * KS_];
      short8 kf0 = *(const short8*)(kp + k8);
      short8 kf1 = *(const short8*)(kp + 32 + k8);
      floatx4 a = (floatx4){0.f, 0.f, 0.f, 0.f};
      a = __builtin_amdgcn_mfma_f32_16x16x32_bf16(qf0, kf0, a, 0, 0, 0);
      a = __builtin_amdgcn_mfma_f32_16x16x32_bf16(qf1, kf1, a, 0, 0, 0);
      s[kt] = a;
    }

    // mask pad cols (tile 12, cols 196..207) before max
    if (lrow >= 4)
      s[12] = (floatx4){-INFINITY, -INFINITY, -INFINITY, -INFINITY};

    // row max + exp + row sum (rows = quad*4+r, cols spread over 16 lanes)
    float mx[4], sum[4];
#pragma unroll
    for (int r = 0; r < 4; ++r) {
      float m2 = s[0][r];
#pragma unroll
      for (int kt = 1; kt < 13; ++kt) m2 = fmaxf(m2, s[kt][r]);
#pragma unroll
      for (int xm = 1; xm < 16; xm <<= 1) m2 = fmaxf(m2, __shfl_xor(m2, xm, 64));
      mx[r] = m2;
    }
#pragma unroll
    for (int r = 0; r < 4; ++r) {
      float sm = 0.f;
#pragma unroll
      for (int kt = 0; kt < 13; ++kt) {
        float p = __expf((s[kt][r] - mx[r]) * 0.125f);   // scale folded in
        s[kt][r] = p;
        sm += p;
      }
#pragma unroll
      for (int xm = 1; xm < 16; xm <<= 1) sm += __shfl_xor(sm, xm, 64);
      sum[r] = sm;
    }

    // P: C/D layout -> LDS (bf16), pad cols 208..223 zeroed
    ushort_t* pw = Ps[qt];
#pragma unroll
    for (int kt = 0; kt < 13; ++kt)
#pragma unroll
      for (int r = 0; r < 4; ++r)
        pw[(quad * 4 + r) * PS_ + kt * 16 + lrow] = f2bf(s[kt][r]);
#pragma unroll
    for (int r = 0; r < 4; ++r)
      pw[(quad * 4 + r) * PS_ + 208 + lrow] = 0;

    // O = P V : A-frag from Ps, B-frag from Vt, 7 k-steps of 32 (224 cols)
    floatx4 o[4];
#pragma unroll
    for (int nt = 0; nt < 4; ++nt) o[nt] = (floatx4){0.f, 0.f, 0.f, 0.f};
#pragma unroll
    for (int kt = 0; kt < 7; ++kt) {
      short8 pf = *(const short8*)&pw[lrow * PS_ + kt * 32 + k8];
#pragma unroll
      for (int nt = 0; nt < 4; ++nt) {
        short8 vf = *(const short8*)&Vt[(nt * 16 + lrow) * VS_ + kt * 32 + k8];
        o[nt] = __builtin_amdgcn_mfma_f32_16x16x32_bf16(pf, vf, o[nt], 0, 0, 0);
      }
    }

    // normalize, stage into the (now dead) P region, write coalesced rows
    float inv[4];
#pragma unroll
    for (int r = 0; r < 4; ++r) inv[r] = 1.f / sum[r];
#pragma unroll
    for (int nt = 0; nt < 4; ++nt)
#pragma unroll
      for (int r = 0; r < 4; ++r)
        pw[(quad * 4 + r) * 64 + nt * 16 + lrow] = f2bf(o[nt][r] * inv[r]);
#pragma unroll
    for (int tr = 0; tr < 16; ++tr) {
      int qr = qt * 16 + tr;
      if (qr < N_)
        x1[(size_t)(bt * N_ + qr) * C_ + hofs + lane] = pw[tr * 64 + lane];
    }
  }
}

// ---------------------------------------------------------------------------
// Temporal attention. One WAVE per (b,h,n); T=16 rows, hd=64. 6 MFMAs/wave
// + 16-lane shfl softmax; per-wave LDS tiles, no __syncthreads.
// Fused avg 0.5*(x1+x2) via wave-private LDS [16][64] O-tile: the global
// RMW is 16 rows of 128 B contiguous.
// LDS/block: Pt 5.1K + Vw 20.5K + Ot 8.2K = 33.8 KB -> 4 blocks/CU.
// ---------------------------------------------------------------------------
__global__ __launch_bounds__(256) void fsta_temporal(
    const ushort_t* __restrict__ qkv, ushort_t* __restrict__ xavg)
{
  __shared__ ushort_t Pt[4][16 * TS_];   // per-wave P   [t][s]   1,280 B each
  __shared__ ushort_t Vw[4][64 * TS_];   // per-wave V^T [d][s]   5,120 B each
  __shared__ ushort_t Ot[4][16 * 64];    // per-wave O   [t][d]   2,048 B each
  const int tid  = threadIdx.x;
  const int lane = tid & 63;
  const int wv   = tid >> 6;
  const int gw   = blockIdx.x * 4 + wv;    // global wave id = (b,h,n)
  const int n    = gw % N_;
  const int bh   = gw / N_;
  const int h    = bh % H_;
  const int b    = bh / H_;
  const int hofs = h * 64;
  const int lrow = lane & 15;
  const int quad = lane >> 4;
  const int k8   = quad * 8;

  ushort_t* pw = Pt[wv];
  ushort_t* vw = Vw[wv];

  // zero pad cols s=16..31 of P and V^T (K=32 MFMA step = 16 real + 16 zero)
  for (int i = lane; i < 16 * 16; i += 64)
    pw[(i >> 4) * TS_ + 16 + (i & 15)] = 0;
  for (int i = lane; i < 64 * 16; i += 64)
    vw[(i >> 4) * TS_ + 16 + (i & 15)] = 0;

  // stage V^T: V rows s=0..15 (64 dims) -> vw[d][s]
  for (int i = lane; i < 128; i += 64) {
    int s = i >> 3, c8 = (i & 7) * 8;
    size_t vo = ((size_t)((b * T_ + s) * N_ + n)) * C3_ + hofs + 1536 + c8;
    ushort_t tmp[8];
    *(uint4*)tmp = *(const uint4*)(qkv + vo);
#pragma unroll
    for (int j = 0; j < 8; ++j) vw[(c8 + j) * TS_ + s] = tmp[j];
  }

  // Q (A-frag, row t=lrow) and K (B-frag, row s=lrow) straight from global
  const size_t ro = ((size_t)((b * T_ + lrow) * N_ + n)) * C3_ + hofs;
  short8 qf0 = *(const short8*)(qkv + ro + k8);
  short8 qf1 = *(const short8*)(qkv + ro + 32 + k8);
  short8 kf0 = *(const short8*)(qkv + ro + 768 + k8);
  short8 kf1 = *(const short8*)(qkv + ro + 800 + k8);

  // S = Q K^T : C layout row = quad*4+r (t), col = lrow (s)
  floatx4 s4 = (floatx4){0.f, 0.f, 0.f, 0.f};
  s4 = __builtin_amdgcn_mfma_f32_16x16x32_bf16(qf0, kf0, s4, 0, 0, 0);
  s4 = __builtin_amdgcn_mfma_f32_16x16x32_bf16(qf1, kf1, s4, 0, 0, 0);

  // softmax over the 16 cols (one per lane within the quad group)
  float inv[4];
#pragma unroll
  for (int r = 0; r < 4; ++r) {
    float m2 = s4[r];
#pragma unroll
    for (int xm = 1; xm < 16; xm <<= 1) m2 = fmaxf(m2, __shfl_xor(m2, xm, 64));
    float p = __expf((s4[r] - m2) * 0.125f);   // scale folded in
    float sm = p;
#pragma unroll
    for (int xm = 1; xm < 16; xm <<= 1) sm += __shfl_xor(sm, xm, 64);
    pw[(quad * 4 + r) * TS_ + lrow] = f2bf(p);
    inv[r] = 1.f / sm;
  }

  // O = P V : A-frag from Pt (rows t=lrow), B-frag from Vw; one K=32 step
  short8 pf = *(const short8*)&pw[lrow * TS_ + k8];
  floatx4 o[4];
#pragma unroll
  for (int nt = 0; nt < 4; ++nt) {
    short8 vf = *(const short8*)&vw[(nt * 16 + lrow) * TS_ + k8];
    o[nt] = __builtin_amdgcn_mfma_f32_16x16x32_bf16(
        pf, vf, (floatx4){0.f, 0.f, 0.f, 0.f}, 0, 0, 0);
  }

  // stage normalized O to wave-private LDS [t][d]
  ushort_t* ow = Ot[wv];
#pragma unroll
  for (int nt = 0; nt < 4; ++nt)
#pragma unroll
    for (int r = 0; r < 4; ++r)
      ow[(quad * 4 + r) * 64 + nt * 16 + lrow] = f2bf(o[nt][r] * inv[r]);

  // fused 0.5*(x1+x2): row t = 64 lanes x 2B = 128 B contiguous RMW
  const size_t obase = ((size_t)(b * T_) * N_ + n) * C_ + hofs + lane;
#pragma unroll
  for (int t = 0; t < T_; ++t) {
    size_t xo = obase + (size_t)t * (N_ * C_);
    float prev = bf2f(xavg[xo]);
    xavg[xo] = f2bf(0.5f * (prev + bf2f(ow[t * 64 + lane])));
  }
}

// ---------------------------------------------------------------------------
// ws layout (bf16 elements):
//   WtQkv  @ 0          : 2304*768   = 1,769,472
//   WtProj @ 1,769,472  : 768*768    =   589,824
//   xbf    @ 2,359,296  : 25088*768  = 19,267,584   (aliased as xavg later)
//   qkv    @ 21,626,880 : 25088*2304 = 57,802,752
// total 79,429,632 elems = 158.9 MB
// ---------------------------------------------------------------------------
extern "C" void kernel_launch(void* const* d_in, const int* in_sizes, int n_in,
                              void* d_out, int out_size, void* d_ws, size_t ws_size,
                              hipStream_t stream)
{
  (void)in_sizes; (void)n_in; (void)out_size; (void)ws_size;
  const float* x     = (const float*)d_in[0];
  const float* Wqkv  = (const float*)d_in[1];
  const float* Wproj = (const float*)d_in[2];
  const float* bproj = (const float*)d_in[3];
  float*    out = (float*)d_out;
  ushort_t* ws  = (ushort_t*)d_ws;

  ushort_t* WtQkv  = ws;
  ushort_t* WtProj = ws + 1769472;
  ushort_t* xbf    = ws + 2359296;   // also xavg after spatial
  ushort_t* xavg   = xbf;
  ushort_t* qkv    = ws + 21626880;

  // 1. fused prep: x -> bf16, W_qkv / W_proj -> transposed bf16 (LDS tiles)
  fsta_prep<<<dim3(11712), dim3(256), 0, stream>>>(
      x, xbf, Wqkv, WtQkv, Wproj, WtProj);
  // 2. qkv = x @ W_qkv   : M=25088, N=2304, K=768   (bf16 out, 98x9 tiles)
  fsta_gemm256<ushort_t><<<dim3(98, 9), dim3(512), 0, stream>>>(
      xbf, WtQkv, (const float*)nullptr, qkv, 2304, 768);
  // 3. spatial attention (MFMA, 13 waves, 1 q-tile/wave) -> xavg
  fsta_spatial<<<dim3(B_ * T_ * H_), dim3(832), 0, stream>>>(qkv, xavg);
  // 4. temporal attention (MFMA, 1 wave per (b,h,n)), fused 0.5*(x1+x2)
  fsta_temporal<<<dim3((B_ * H_ * N_) / 4), dim3(256), 0, stream>>>(qkv, xavg);
  // 5. out = xavg @ W_proj + b_proj : M=25088, N=768, K=768  (fp32, 98x3 tiles)
  fsta_gemm256<float><<<dim3(98, 3), dim3(512), 0, stream>>>(
      xavg, WtProj, bproj, out, 768, 768);
}

// Round 13
// 389.135 us; speedup vs baseline: 1.1415x; 1.0146x over previous
//
#include <hip/hip_runtime.h>
#include <cstdint>
#include <cstddef>

typedef unsigned short ushort_t;
typedef unsigned int   uint_t;

#define B_   8
#define T_   16
#define N_   196
#define C_   768
#define H_   12
#define C3_  2304
#define M_   25088   // B_*T_*N_

// spatial-attention tiling
#define NP_  208     // N padded to 13 tiles of 16
#define KS_  72      // K LDS row stride (elems): 144 B, 16B-aligned, 2-way alias
#define VS_  232     // V^T LDS row stride: 464 B, 16B-aligned, 2-way alias
#define PS_  232     // P LDS row stride

// temporal-attention tiling
#define TS_  40      // LDS row stride (elems): 80 B, 16B-aligned, 2-way alias

typedef __attribute__((ext_vector_type(8))) short short8;
typedef __attribute__((ext_vector_type(4))) float floatx4;

__device__ __forceinline__ float bf2f(ushort_t u) {
  return __uint_as_float(((uint_t)u) << 16);
}
__device__ __forceinline__ ushort_t f2bf(float f) {
  uint_t u = __float_as_uint(f);
  u += 0x7FFFu + ((u >> 16) & 1u);   // round-to-nearest-even
  return (ushort_t)(u >> 16);
}
__device__ __forceinline__ uint_t pack2(float a, float b) {
  return (uint_t)f2bf(a) | ((uint_t)f2bf(b) << 16);
}

// async global->LDS, 16 B per lane. LDS dest = wave-uniform base + lane*16.
__device__ __forceinline__ void gload_lds16(const ushort_t* g, ushort_t* l) {
  __builtin_amdgcn_global_load_lds(
      (const __attribute__((address_space(1))) uint_t*)g,
      (__attribute__((address_space(3))) uint_t*)l, 16, 0, 0);
}

// raw barrier: compiler memory fence + s_barrier + scheduler pin.
// (NOT __syncthreads(): that drains vmcnt(0) and would kill the counted
// prefetch pipeline.)
__device__ __forceinline__ void bar() {
  asm volatile("" ::: "memory");
  __builtin_amdgcn_s_barrier();
  __builtin_amdgcn_sched_barrier(0);
}

// ---------------------------------------------------------------------------
// Fused prep (one dispatch):
//   blocks [0, 9408)        : x fp32 -> bf16, 8 elems/thread (19,267,584)
//   blocks [9408, 11136)    : W_qkv [768][2304] -> bf16 [2304][768], 32x32
//                             LDS tile transpose (coalesced reads AND writes)
//   blocks [11136, 11712)   : W_proj [768][768] -> bf16 [768][768], same
// ---------------------------------------------------------------------------
__global__ void fsta_prep(const float* __restrict__ x,
                          ushort_t* __restrict__ xbf,
                          const float* __restrict__ Wqkv,
                          ushort_t* __restrict__ WtQkv,
                          const float* __restrict__ Wproj,
                          ushort_t* __restrict__ WtProj)
{
  __shared__ float tile[32][33];
  const int bid = blockIdx.x;
  const int tid = threadIdx.x;
  if (bid < 9408) {
    int i = (bid * 256 + tid) * 8;
    const float* f = x + i;
    uint4 u;
    u.x = pack2(f[0], f[1]); u.y = pack2(f[2], f[3]);
    u.z = pack2(f[4], f[5]); u.w = pack2(f[6], f[7]);
    *(uint4*)(xbf + i) = u;
    return;
  }
  const float* src; ushort_t* dst; int Cc, rt, ct;
  if (bid < 11136) {
    int b2 = bid - 9408;                 // 1728 blocks = 24 rt x 72 ct
    src = Wqkv; dst = WtQkv; Cc = 2304; ct = b2 % 72; rt = b2 / 72;
  } else {
    int b2 = bid - 11136;                // 576 blocks = 24 x 24
    src = Wproj; dst = WtProj; Cc = 768; ct = b2 % 24; rt = b2 / 24;
  }
  const int tx = tid & 31, ty = tid >> 5;
#pragma unroll
  for (int i = 0; i < 4; ++i)
    tile[ty + i * 8][tx] =
        src[(size_t)(rt * 32 + ty + i * 8) * Cc + ct * 32 + tx];
  __syncthreads();
#pragma unroll
  for (int i = 0; i < 4; ++i)
    dst[(size_t)(ct * 32 + ty + i * 8) * 768 + rt * 32 + tx] =
        f2bf(tile[tx][ty + i * 8]);
}

// ---------------------------------------------------------------------------
// ROUND-9 GEMM: occupancy-first 128x128 / BK=32 / 4 waves (2Mx2N, 64x64 per
// wave, acc[4][4] = 64 regs -> ~120 total/wave) / LDS 32 KiB (2 x 16 KiB
// double buffer) ==> 4 INDEPENDENT blocks per CU (16 waves/CU vs 8 before).
// Round-8 counters showed the 256^2 8-phase kernel pinned at 1 lockstep
// block/CU (128 KiB LDS + 256 regs/wave): per ~2000-cycle phase only ~620
// cycles were MFMA and nothing else could fill the rest. 4 independent
// blocks/CU hide each other's barriers/guards/ds_reads.
//   per iteration (24 of them, K=768):
//     ds_read af[4]+bf[4] (tile t, buf t&1)
//     vmcnt(0)  <- waits stage(t+1), issued a FULL iteration ago (not a
//                  drain of fresh loads; stage(t+2) isn't issued yet)
//     bar(); 16 MFMA in setprio(1); STG tile t+2 -> buf t&1 (region's reads
//     all consumed; other waves' reads were issued pre-bar and the gload
//     write lands >=500 cyc later); bar()
// T2 swizzle kept verbatim (64-B rows): slot = chunk ^ ((row>>1)&3);
// verified round 4 (SQ_LDS_BANK_CONFLICT 8.1M -> 0). XCD swizzle + n-inner
// tile order kept (verified round 8: FETCH 177 -> 79.6 MB).
// ---------------------------------------------------------------------------
#define STG1(X, rb, bu, xo, t)                                                \
  { _Pragma("unroll") for (int c_ = 0; c_ < 2; ++c_) {                        \
      const ushort_t* g_ = (X) +                                              \
          (size_t)((rb) + c_ * 64 + wv * 16 + srow) * K +                     \
          (t) * 32 + chnk * 8;                                                \
      gload_lds16(g_, &lds[(bu) * 8192 + (xo) + c_ * 2048 + wv * 512]); } }

#define GUARD4 asm volatile("s_waitcnt vmcnt(4)" ::: "memory");
#define GUARD0 asm volatile("s_waitcnt vmcnt(0)" ::: "memory");

template <typename OutT>
__global__ __launch_bounds__(256, 4) void fsta_gemm128(
    const ushort_t* __restrict__ A1,
    const ushort_t* __restrict__ Bt,
    const float* __restrict__ bias,
    OutT* __restrict__ Cout,
    int Ncols, int K)
{
  __shared__ ushort_t lds[16384];          // 32 KiB: 2 buf x {A[128][32], B[128][32]}
  const int tid  = threadIdx.x;
  const int lane = tid & 63;
  const int wv   = tid >> 6;               // 0..3
  const int wm   = wv >> 1;                // 0..1 (M half)
  const int wn   = wv & 1;                 // 0..1 (N half)
  const int lrow = lane & 15;
  const int quad = lane >> 4;
  const int rch8 = (quad ^ ((lrow >> 1) & 3)) * 8;  // swizzled read chunk
  const int srow = lane >> 2;                       // staging row-in-16
  const int chnk = (lane & 3) ^ ((srow >> 1) & 3);  // inverse-swizzled src

  // bijective XCD-chunk swizzle (m204 formula; both grids are %8==0)
  const int ntx = gridDim.x;
  const int gdy = gridDim.y;
  const int nwg = ntx * gdy;
  int lin = blockIdx.y * ntx + blockIdx.x;
  {
    int q = nwg >> 3, r = nwg & 7;
    int xcd = lin & 7, off = lin >> 3;
    lin = (xcd < r ? xcd * (q + 1) : r * (q + 1) + (xcd - r) * q) + off;
  }
  // n-INNER tile order: consecutive lin share the A-panel (L2-resident)
  const int m0 = (lin / gdy) * 128;
  const int n0 = (lin % gdy) * 128;

  const int NT = K >> 5;                   // 32-wide K-tiles (24)

  floatx4 acc[4][4];
#pragma unroll
  for (int i = 0; i < 4; ++i)
#pragma unroll
    for (int j = 0; j < 4; ++j)
      acc[i][j] = (floatx4){0.f, 0.f, 0.f, 0.f};

  // prologue: tiles 0,1 into buffers 0,1 (8 loads/thread); wait tile0 only
  STG1(A1, m0, 0, 0,    0)
  STG1(Bt, n0, 0, 4096, 0)
  STG1(A1, m0, 1, 0,    1)
  STG1(Bt, n0, 1, 4096, 1)
  GUARD4
  bar();

  for (int t = 0; t < NT; ++t) {
    const int bu = t & 1;
    short8 af[4], bfr[4];
#pragma unroll
    for (int m2 = 0; m2 < 4; ++m2)
      af[m2] = *(const short8*)&lds[bu * 8192 +
                                    (wm * 64 + m2 * 16 + lrow) * 32 + rch8];
#pragma unroll
    for (int n2 = 0; n2 < 4; ++n2)
      bfr[n2] = *(const short8*)&lds[bu * 8192 + 4096 +
                                     (wn * 64 + n2 * 16 + lrow) * 32 + rch8];
    GUARD0                               // stage(t+1) landed (1-iter lead)
    bar();
    __builtin_amdgcn_s_setprio(1);
#pragma unroll
    for (int m2 = 0; m2 < 4; ++m2)
#pragma unroll
      for (int n2 = 0; n2 < 4; ++n2)
        acc[m2][n2] = __builtin_amdgcn_mfma_f32_16x16x32_bf16(
            af[m2], bfr[n2], acc[m2][n2], 0, 0, 0);
    __builtin_amdgcn_s_setprio(0);
    if (t + 2 < NT) {                    // overwrite fully-consumed buf[bu]
      STG1(A1, m0, bu, 0,    t + 2)
      STG1(Bt, n0, bu, 4096, t + 2)
    }
    bar();
  }

  // epilogue: C/D layout col=lane&15, row=quad*4+reg
#pragma unroll
  for (int m2 = 0; m2 < 4; ++m2) {
    int row = m0 + wm * 64 + m2 * 16 + quad * 4;
#pragma unroll
    for (int n2 = 0; n2 < 4; ++n2) {
      int col = n0 + wn * 64 + n2 * 16 + lrow;
      float badd = bias ? bias[col] : 0.f;
#pragma unroll
      for (int rr = 0; rr < 4; ++rr) {
        float v = acc[m2][n2][rr] + badd;
        if constexpr (sizeof(OutT) == 4)
          Cout[(size_t)(row + rr) * Ncols + col] = v;
        else
          Cout[(size_t)(row + rr) * Ncols + col] = (OutT)f2bf(v);
      }
    }
  }
}

// ---------------------------------------------------------------------------
// Spatial attention: 13 waves (832 threads), exactly ONE q-tile per wave.
// LDS: Ks 29,952 + Vt 29,696 + Ps[13] 96,512 = 156,160 B <= 160 KiB.
// O reuses the (dead) P region for the coalesced 128 B-row epilogue.
// FROZEN this round (round-8 anchor).
// ---------------------------------------------------------------------------
__global__ __launch_bounds__(832) void fsta_spatial(
    const ushort_t* __restrict__ qkv, ushort_t* __restrict__ x1)
{
  __shared__ ushort_t Ks[NP_ * KS_];       // [key][dim]   29,952 B
  __shared__ ushort_t Vt[64 * VS_];        // [dim][key]   29,696 B
  __shared__ ushort_t Ps[13][16 * PS_];    // per-wave P   96,512 B
  const int tid = threadIdx.x;
  const int bid = blockIdx.x;
  const int h   = bid % H_;
  const int bt  = bid / H_;
  const size_t rowbase = (size_t)bt * N_ * C3_;
  const int hofs = h * 64;

  // stage K row-major and V transposed
  for (int idx = tid; idx < N_ * 8; idx += 832) {
    int n = idx >> 3, c = (idx & 7) * 8;
    size_t so = rowbase + (size_t)n * C3_ + hofs + c;
    *(uint4*)&Ks[n * KS_ + c] = *(const uint4*)(qkv + so + 768);
    uint4 v = *(const uint4*)(qkv + so + 1536);
    ushort_t tmp[8];
    *(uint4*)tmp = v;
#pragma unroll
    for (int i = 0; i < 8; ++i) Vt[(c + i) * VS_ + n] = tmp[i];
  }
  // zero V^T pad cols 196..231
  for (int idx = tid; idx < 64 * (VS_ - N_); idx += 832) {
    int d = idx / (VS_ - N_), k = N_ + idx % (VS_ - N_);
    Vt[d * VS_ + k] = 0;
  }
  __syncthreads();

  const int lane = tid & 63;
  const int qt   = tid >> 6;               // wave id == q-tile id, 0..12
  const int lrow = lane & 15;
  const int quad = lane >> 4;
  const int k8   = quad * 8;

  {
    // Q A-frags straight from global (rows clamped; results discarded at store)
    int qrow = qt * 16 + lrow; if (qrow > N_ - 1) qrow = N_ - 1;
    const ushort_t* qp = qkv + rowbase + (size_t)qrow * C3_ + hofs;
    short8 qf0 = *(const short8*)(qp + k8);
    short8 qf1 = *(const short8*)(qp + 32 + k8);

    // S = Q K^T : 13 key tiles, K-dim 64 = 2 MFMA steps
    floatx4 s[13];
#pragma unroll
    for (int kt = 0; kt < 13; ++kt) {
      const ushort_t* kp = &Ks[(kt * 16 + lrow) * KS_];
      short8 kf0 = *(const short8*)(kp + k8);
      short8 kf1 = *(const short8*)(kp + 32 + k8);
      floatx4 a = (floatx4){0.f, 0.f, 0.f, 0.f};
      a = __builtin_amdgcn_mfma_f32_16x16x32_bf16(qf0, kf0, a, 0, 0, 0);
      a = __builtin_amdgcn_mfma_f32_16x16x32_bf16(qf1, kf1, a, 0, 0, 0);
      s[kt] = a;
    }

    // mask pad cols (tile 12, cols 196..207) before max
    if (lrow >= 4)
      s[12] = (floatx4){-INFINITY, -INFINITY, -INFINITY, -INFINITY};

    // row max + exp + row sum (rows = quad*4+r, cols spread over 16 lanes)
    float mx[4], sum[4];
#pragma unroll
    for (int r = 0; r < 4; ++r) {
      float m2 = s[0][r];
#pragma unroll
      for (int kt = 1; kt < 13; ++kt) m2 = fmaxf(m2, s[kt][r]);
#pragma unroll
      for (int xm = 1; xm < 16; xm <<= 1) m2 = fmaxf(m2, __shfl_xor(m2, xm, 64));
      mx[r] = m2;
    }
#pragma unroll
    for (int r = 0; r < 4; ++r) {
      float sm = 0.f;
#pragma unroll
      for (int kt = 0; kt < 13; ++kt) {
        float p = __expf((s[kt][r] - mx[r]) * 0.125f);   // scale folded in
        s[kt][r] = p;
        sm += p;
      }
#pragma unroll
      for (int xm = 1; xm < 16; xm <<= 1) sm += __shfl_xor(sm, xm, 64);
      sum[r] = sm;
    }

    // P: C/D layout -> LDS (bf16), pad cols 208..223 zeroed
    ushort_t* pw = Ps[qt];
#pragma unroll
    for (int kt = 0; kt < 13; ++kt)
#pragma unroll
      for (int r = 0; r < 4; ++r)
        pw[(quad * 4 + r) * PS_ + kt * 16 + lrow] = f2bf(s[kt][r]);
#pragma unroll
    for (int r = 0; r < 4; ++r)
      pw[(quad * 4 + r) * PS_ + 208 + lrow] = 0;

    // O = P V : A-frag from Ps, B-frag from Vt, 7 k-steps of 32 (224 cols)
    floatx4 o[4];
#pragma unroll
    for (int nt = 0; nt < 4; ++nt) o[nt] = (floatx4){0.f, 0.f, 0.f, 0.f};
#pragma unroll
    for (int kt = 0; kt < 7; ++kt) {
      short8 pf = *(const short8*)&pw[lrow * PS_ + kt * 32 + k8];
#pragma unroll
      for (int nt = 0; nt < 4; ++nt) {
        short8 vf = *(const short8*)&Vt[(nt * 16 + lrow) * VS_ + kt * 32 + k8];
        o[nt] = __builtin_amdgcn_mfma_f32_16x16x32_bf16(pf, vf, o[nt], 0, 0, 0);
      }
    }

    // normalize, stage into the (now dead) P region, write coalesced rows
    float inv[4];
#pragma unroll
    for (int r = 0; r < 4; ++r) inv[r] = 1.f / sum[r];
#pragma unroll
    for (int nt = 0; nt < 4; ++nt)
#pragma unroll
      for (int r = 0; r < 4; ++r)
        pw[(quad * 4 + r) * 64 + nt * 16 + lrow] = f2bf(o[nt][r] * inv[r]);
#pragma unroll
    for (int tr = 0; tr < 16; ++tr) {
      int qr = qt * 16 + tr;
      if (qr < N_)
        x1[(size_t)(bt * N_ + qr) * C_ + hofs + lane] = pw[tr * 64 + lane];
    }
  }
}

// ---------------------------------------------------------------------------
// Temporal attention. One WAVE per (b,h,n); T=16 rows, hd=64. 6 MFMAs/wave
// + 16-lane shfl softmax; per-wave LDS tiles, no __syncthreads.
// Fused avg 0.5*(x1+x2) via wave-private LDS [16][64] O-tile: the global
// RMW is 16 rows of 128 B contiguous. FROZEN this round.
// ---------------------------------------------------------------------------
__global__ __launch_bounds__(256) void fsta_temporal(
    const ushort_t* __restrict__ qkv, ushort_t* __restrict__ xavg)
{
  __shared__ ushort_t Pt[4][16 * TS_];   // per-wave P   [t][s]   1,280 B each
  __shared__ ushort_t Vw[4][64 * TS_];   // per-wave V^T [d][s]   5,120 B each
  __shared__ ushort_t Ot[4][16 * 64];    // per-wave O   [t][d]   2,048 B each
  const int tid  = threadIdx.x;
  const int lane = tid & 63;
  const int wv   = tid >> 6;
  const int gw   = blockIdx.x * 4 + wv;    // global wave id = (b,h,n)
  const int n    = gw % N_;
  const int bh   = gw / N_;
  const int h    = bh % H_;
  const int b    = bh / H_;
  const int hofs = h * 64;
  const int lrow = lane & 15;
  const int quad = lane >> 4;
  const int k8   = quad * 8;

  ushort_t* pw = Pt[wv];
  ushort_t* vw = Vw[wv];

  // zero pad cols s=16..31 of P and V^T (K=32 MFMA step = 16 real + 16 zero)
  for (int i = lane; i < 16 * 16; i += 64)
    pw[(i >> 4) * TS_ + 16 + (i & 15)] = 0;
  for (int i = lane; i < 64 * 16; i += 64)
    vw[(i >> 4) * TS_ + 16 + (i & 15)] = 0;

  // stage V^T: V rows s=0..15 (64 dims) -> vw[d][s]
  for (int i = lane; i < 128; i += 64) {
    int s = i >> 3, c8 = (i & 7) * 8;
    size_t vo = ((size_t)((b * T_ + s) * N_ + n)) * C3_ + hofs + 1536 + c8;
    ushort_t tmp[8];
    *(uint4*)tmp = *(const uint4*)(qkv + vo);
#pragma unroll
    for (int j = 0; j < 8; ++j) vw[(c8 + j) * TS_ + s] = tmp[j];
  }

  // Q (A-frag, row t=lrow) and K (B-frag, row s=lrow) straight from global
  const size_t ro = ((size_t)((b * T_ + lrow) * N_ + n)) * C3_ + hofs;
  short8 qf0 = *(const short8*)(qkv + ro + k8);
  short8 qf1 = *(const short8*)(qkv + ro + 32 + k8);
  short8 kf0 = *(const short8*)(qkv + ro + 768 + k8);
  short8 kf1 = *(const short8*)(qkv + ro + 800 + k8);

  // S = Q K^T : C layout row = quad*4+r (t), col = lrow (s)
  floatx4 s4 = (floatx4){0.f, 0.f, 0.f, 0.f};
  s4 = __builtin_amdgcn_mfma_f32_16x16x32_bf16(qf0, kf0, s4, 0, 0, 0);
  s4 = __builtin_amdgcn_mfma_f32_16x16x32_bf16(qf1, kf1, s4, 0, 0, 0);

  // softmax over the 16 cols (one per lane within the quad group)
  float inv[4];
#pragma unroll
  for (int r = 0; r < 4; ++r) {
    float m2 = s4[r];
#pragma unroll
    for (int xm = 1; xm < 16; xm <<= 1) m2 = fmaxf(m2, __shfl_xor(m2, xm, 64));
    float p = __expf((s4[r] - m2) * 0.125f);   // scale folded in
    float sm = p;
#pragma unroll
    for (int xm = 1; xm < 16; xm <<= 1) sm += __shfl_xor(sm, xm, 64);
    pw[(quad * 4 + r) * TS_ + lrow] = f2bf(p);
    inv[r] = 1.f / sm;
  }

  // O = P V : A-frag from Pt (rows t=lrow), B-frag from Vw; one K=32 step
  short8 pf = *(const short8*)&pw[lrow * TS_ + k8];
  floatx4 o[4];
#pragma unroll
  for (int nt = 0; nt < 4; ++nt) {
    short8 vf = *(const short8*)&vw[(nt * 16 + lrow) * TS_ + k8];
    o[nt] = __builtin_amdgcn_mfma_f32_16x16x32_bf16(
        pf, vf, (floatx4){0.f, 0.f, 0.f, 0.f}, 0, 0, 0);
  }

  // stage normalized O to wave-private LDS [t][d]
  ushort_t* ow = Ot[wv];
#pragma unroll
  for (int nt = 0; nt < 4; ++nt)
#pragma unroll
    for (int r = 0; r < 4; ++r)
      ow[(quad * 4 + r) * 64 + nt * 16 + lrow] = f2bf(o[nt][r] * inv[r]);

  // fused 0.5*(x1+x2): row t = 64 lanes x 2B = 128 B contiguous RMW
  const size_t obase = ((size_t)(b * T_) * N_ + n) * C_ + hofs + lane;
#pragma unroll
  for (int t = 0; t < T_; ++t) {
    size_t xo = obase + (size_t)t * (N_ * C_);
    float prev = bf2f(xavg[xo]);
    xavg[xo] = f2bf(0.5f * (prev + bf2f(ow[t * 64 + lane])));
  }
}

// ---------------------------------------------------------------------------
// ws layout (bf16 elements):
//   WtQkv  @ 0          : 2304*768   = 1,769,472
//   WtProj @ 1,769,472  : 768*768    =   589,824
//   xbf    @ 2,359,296  : 25088*768  = 19,267,584   (aliased as xavg later)
//   qkv    @ 21,626,880 : 25088*2304 = 57,802,752
// total 79,429,632 elems = 158.9 MB
// ---------------------------------------------------------------------------
extern "C" void kernel_launch(void* const* d_in, const int* in_sizes, int n_in,
                              void* d_out, int out_size, void* d_ws, size_t ws_size,
                              hipStream_t stream)
{
  (void)in_sizes; (void)n_in; (void)out_size; (void)ws_size;
  const float* x     = (const float*)d_in[0];
  const float* Wqkv  = (const float*)d_in[1];
  const float* Wproj = (const float*)d_in[2];
  const float* bproj = (const float*)d_in[3];
  float*    out = (float*)d_out;
  ushort_t* ws  = (ushort_t*)d_ws;

  ushort_t* WtQkv  = ws;
  ushort_t* WtProj = ws + 1769472;
  ushort_t* xbf    = ws + 2359296;   // also xavg after spatial
  ushort_t* xavg   = xbf;
  ushort_t* qkv    = ws + 21626880;

  // 1. fused prep: x -> bf16, W_qkv / W_proj -> transposed bf16 (LDS tiles)
  fsta_prep<<<dim3(11712), dim3(256), 0, stream>>>(
      x, xbf, Wqkv, WtQkv, Wproj, WtProj);
  // 2. qkv = x @ W_qkv   : M=25088, N=2304, K=768   (bf16 out, 196x18 tiles)
  fsta_gemm128<ushort_t><<<dim3(196, 18), dim3(256), 0, stream>>>(
      xbf, WtQkv, (const float*)nullptr, qkv, 2304, 768);
  // 3. spatial attention (MFMA, 13 waves, 1 q-tile/wave) -> xavg
  fsta_spatial<<<dim3(B_ * T_ * H_), dim3(832), 0, stream>>>(qkv, xavg);
  // 4. temporal attention (MFMA, 1 wave per (b,h,n)), fused 0.5*(x1+x2)
  fsta_temporal<<<dim3((B_ * H_ * N_) / 4), dim3(256), 0, stream>>>(qkv, xavg);
  // 5. out = xavg @ W_proj + b_proj : M=25088, N=768, K=768  (fp32, 196x6 tiles)
  fsta_gemm128<float><<<dim3(196, 6), dim3(256), 0, stream>>>(
      xavg, WtProj, bproj, out, 768, 768);
}